// Round 17
// baseline (815.622 us; speedup 1.0000x reference)
//
#include <hip/hip_runtime.h>
#include <hip/hip_fp16.h>
#include <math.h>

#define DI 384
#define NSEQ 256
#define BB 64
#define DOUT 512
#define SID 73920
#define EPSV 1e-5f

typedef float f32x4 __attribute__((ext_vector_type(4)));
typedef short s16x8 __attribute__((ext_vector_type(8)));
typedef _Float16 f16x8 __attribute__((ext_vector_type(8)));

// ---------------- small kernels ----------------

// invdeg[b][n] = 1/(sum_k graph[b][n][k] + eps); one wave per row, coalesced.
__global__ __launch_bounds__(256) void k_deg(const float* __restrict__ graph,
                                             float* __restrict__ ivd) {
  int row = blockIdx.x * 4 + (threadIdx.x >> 6);  // 16384 rows
  int l = threadIdx.x & 63;
  const float* g = graph + (size_t)row * NSEQ;
  float s = g[l] + g[l + 64] + g[l + 128] + g[l + 192];
#pragma unroll
  for (int o = 32; o > 0; o >>= 1) s += __shfl_down(s, o);
  if (l == 0) ivd[row] = 1.0f / (s + EPSV);
}

// colw 2-stage over weights = graph * invdeg (computed on the fly)
__global__ __launch_bounds__(256) void k_colw1(const float* __restrict__ graph,
                                               const float* __restrict__ ivd,
                                               float* __restrict__ part) {
  int b = blockIdx.x, nc = blockIdx.y;
  int j = threadIdx.x;
  const float* g = graph + (size_t)b * NSEQ * NSEQ + (size_t)nc * 32 * NSEQ + j;
  const float* iv = ivd + b * NSEQ + nc * 32;
  float s = 0.f;
#pragma unroll
  for (int n = 0; n < 32; n++) s += g[(size_t)n * NSEQ] * iv[n];
  part[((size_t)nc * BB + b) * NSEQ + j] = s;
}

__global__ __launch_bounds__(256) void k_colw2(const float* __restrict__ part,
                                               float* __restrict__ colw) {
  int idx = blockIdx.x * 256 + threadIdx.x;  // 64*256
  float s = 0.f;
#pragma unroll
  for (int nc = 0; nc < 8; nc++) s += part[(size_t)nc * BB * NSEQ + idx];
  colw[idx] = s;
}

// wmean 2-stage: wm[b][d] = sum_n colw[b][n]*tokens[b][n][d]
__global__ __launch_bounds__(384) void k_wmean1(const float* __restrict__ colw,
                                                const float* __restrict__ tokens,
                                                float* __restrict__ part) {
  int b = blockIdx.x, nc = blockIdx.y;
  int d = threadIdx.x;
  const float* t = tokens + (size_t)b * NSEQ * DI + (size_t)nc * 32 * DI + d;
  const float* cw = colw + b * NSEQ + nc * 32;
  float s = 0.f;
#pragma unroll
  for (int n = 0; n < 32; n++) s += cw[n] * t[(size_t)n * DI];
  part[((size_t)nc * BB + b) * DI + d] = s;
}

__global__ __launch_bounds__(256) void k_wmean2(const float* __restrict__ part,
                                                float* __restrict__ wm) {
  int idx = blockIdx.x * 256 + threadIdx.x;  // 64*384
  float s = 0.f;
#pragma unroll
  for (int nc = 0; nc < 8; nc++) s += part[(size_t)nc * BB * DI + idx];
  wm[idx] = s;
}

// ZT[b][d][n] = tokens[b][n][d] - wm[b][d]
__global__ __launch_bounds__(256) void k_zcT(const float* __restrict__ tokens,
                                             const float* __restrict__ wm,
                                             float* __restrict__ ZT) {
  int b = blockIdx.z;
  int d0 = blockIdx.x * 64, n0 = blockIdx.y * 64;
  __shared__ float ld[64][68];
  const float* Tb = tokens + (size_t)b * NSEQ * DI;
  const float* wmb = wm + (size_t)b * DI;
  float* Zb = ZT + (size_t)b * DI * NSEQ;
#pragma unroll
  for (int i = 0; i < 4; i++) {
    int sl = threadIdx.x + i * 256;
    int r = sl >> 4, q = sl & 15;
    float4 v = *(const float4*)&Tb[(size_t)(n0 + r) * DI + d0 + q * 4];
    float4 m = *(const float4*)&wmb[d0 + q * 4];
    v.x -= m.x; v.y -= m.y; v.z -= m.z; v.w -= m.w;
    *(float4*)&ld[r][q * 4] = v;
  }
  __syncthreads();
#pragma unroll
  for (int i = 0; i < 4; i++) {
    int sl = threadIdx.x + i * 256;
    int dl = sl >> 4, q = sl & 15;
    float4 v;
    v.x = ld[q * 4 + 0][dl];
    v.y = ld[q * 4 + 1][dl];
    v.z = ld[q * 4 + 2][dl];
    v.w = ld[q * 4 + 3][dl];
    *(float4*)&Zb[(size_t)(d0 + dl) * NSEQ + n0 + q * 4] = v;
  }
}

__global__ __launch_bounds__(256) void k_trace(const float* __restrict__ M2,
                                               float* __restrict__ tr) {
  int b = blockIdx.x;
  int t = threadIdx.x;
  float s = 0.f;
  for (int d = t; d < DI; d += 256)
    s += M2[(size_t)b * DI * DI + (size_t)d * DI + d];
  __shared__ float red[256];
  red[t] = s;
  __syncthreads();
  for (int st = 128; st > 0; st >>= 1) {
    if (t < st) red[t] += red[t + st];
    __syncthreads();
  }
  if (t == 0) tr[b] = red[0];
}

// ---------------- fp16 2-plane split helpers --------------------------------

__device__ __forceinline__ int swzB(int row, int s) {
  return (((row << 2) + s) ^ ((row >> 1) & 7)) << 3;  // in shorts
}

__device__ __forceinline__ unsigned splitpair_h(float a, float c, float& ra,
                                                float& rc) {
  __half2 h = __float22half2_rn(make_float2(a, c));
  unsigned u;
  __builtin_memcpy(&u, &h, 4);
  ra = a - __low2float(h);
  rc = c - __high2float(h);
  return u;
}

__device__ __forceinline__ unsigned packh2(float a, float c) {
  __half2 h = __float22half2_rn(make_float2(a, c));
  unsigned u;
  __builtin_memcpy(&u, &h, 4);
  return u;
}

__device__ __forceinline__ void split8v(float x0, float x1, float x2, float x3,
                                        float x4, float x5, float x6, float x7,
                                        short* dst, int ps) {
  unsigned h0, h1, h2, h3, m0, m1, m2, m3;
  float ra, rc;
  h0 = splitpair_h(x0, x1, ra, rc); m0 = packh2(ra, rc);
  h1 = splitpair_h(x2, x3, ra, rc); m1 = packh2(ra, rc);
  h2 = splitpair_h(x4, x5, ra, rc); m2 = packh2(ra, rc);
  h3 = splitpair_h(x6, x7, ra, rc); m3 = packh2(ra, rc);
  uint4 H, M;
  H.x = h0; H.y = h1; H.z = h2; H.w = h3;
  M.x = m0; M.y = m1; M.z = m2; M.w = m3;
  *(uint4*)(dst) = H;
  *(uint4*)(dst + ps) = M;
}

__device__ __forceinline__ void split8_h(f32x4 v0, f32x4 v1, short* dst, int ps) {
  split8v(v0[0], v0[1], v0[2], v0[3], v1[0], v1[1], v1[2], v1[3], dst, ps);
}

__device__ __forceinline__ f16x8 ldfrag(const short* p) {
  s16x8 t = *(const s16x8*)p;
  return __builtin_bit_cast(f16x8, t);
}

// ---------------- fp16-split MFMA GEMM --------------------------------------
// (256,4): r16 post-mortem -- (256,3) win confirmed latency/occupancy is the
// binding constraint; LDS 32 KB allows 5 blocks/CU, VGPR cap 128 is the probe.
// Failure signature to watch (r6): WRITE_SIZE ballooning + VGPR_Count drop.
template <int MODE, int BSTAGE, int ASCL, int BSCL, int BRSCL>
__global__ __launch_bounds__(256, 4) void gemm_k(
    const float* __restrict__ pA, const float* __restrict__ pB,
    float* __restrict__ pC, const float* __restrict__ pMn,
    const float* __restrict__ pP1, const float* __restrict__ trv,
    const float* __restrict__ pRScl, int K, int lda, int ldb, long sA, long sB,
    long sC, float alpha, float diagAdd, int ntn, int ntile) {
  __shared__ short As[2 * 128 * 32];
  __shared__ short Bs[2 * 128 * 32];
  int flat = blockIdx.x;
  int q = flat >> 3;
  int b = (flat & 7) + (q / ntile) * 8;
  int tk = q % ntile;
  int m0 = (tk / ntn) * 128;
  int n0 = (tk % ntn) * 128;
  int tid = threadIdx.x;
  int lane = tid & 63, wid = tid >> 6;
  int wm = wid >> 1, wn = wid & 1;
  int lr = lane & 15, lg = lane >> 4;
  float inv = 0.f;
  if (ASCL || BSCL || MODE == 1) inv = 1.0f / (trv[b] + EPSV);

  int rowA = tid >> 1, subA = tid & 1;
  int oA0 = swzB(rowA, 2 * subA), oA1 = swzB(rowA, 2 * subA + 1);
  const float* Aptr = pA + (size_t)b * sA + (size_t)(m0 + rowA) * lda + subA * 16;

  int rowB = tid >> 1;
  const float* Bptr;
  int oB0, oB1;
  float rscl = 1.f;
  if (BSTAGE == 0) {
    int subB = tid & 1;
    oB0 = swzB(rowB, 2 * subB);
    oB1 = swzB(rowB, 2 * subB + 1);
    Bptr = pB + (size_t)b * sB + (size_t)(n0 + rowB) * ldb + subB * 16;
    if (BRSCL) rscl = pRScl[(size_t)b * NSEQ + n0 + rowB];
  } else {
    int nB = (tid & 63) * 2, kk8 = (tid >> 6) * 8;
    oB0 = swzB(nB, kk8 >> 3);
    oB1 = swzB(nB + 1, kk8 >> 3);
    Bptr = pB + (size_t)b * sB + (size_t)kk8 * ldb + n0 + nB;
  }

  f32x4 acc[4][4] = {};
  f32x4 a0, a1, a2, a3;
  f32x4 t0, t1, t2, t3;
  float2 q0, q1, q2, q3, q4, q5, q6, q7;

#define LOAD_A(OFF)                      \
  a0 = *(const f32x4*)(Aptr + (OFF));    \
  a1 = *(const f32x4*)(Aptr + (OFF) + 4);\
  a2 = *(const f32x4*)(Aptr + (OFF) + 8);\
  a3 = *(const f32x4*)(Aptr + (OFF) + 12);

#define STORE_A()                                            \
  {                                                          \
    if (ASCL) { a0 *= inv; a1 *= inv; a2 *= inv; a3 *= inv; }\
    split8_h(a0, a1, As + oA0, 4096);                        \
    split8_h(a2, a3, As + oA1, 4096);                        \
  }

#define LOAD_B(OFF)                                              \
  if (BSTAGE == 0) {                                             \
    t0 = *(const f32x4*)(Bptr + (OFF));                          \
    t1 = *(const f32x4*)(Bptr + (OFF) + 4);                      \
    t2 = *(const f32x4*)(Bptr + (OFF) + 8);                      \
    t3 = *(const f32x4*)(Bptr + (OFF) + 12);                     \
  } else {                                                       \
    const float* bp = Bptr + (size_t)(OFF) * ldb;                \
    q0 = *(const float2*)(bp);                                   \
    q1 = *(const float2*)(bp + ldb);                             \
    q2 = *(const float2*)(bp + 2 * ldb);                         \
    q3 = *(const float2*)(bp + 3 * ldb);                         \
    q4 = *(const float2*)(bp + 4 * ldb);                         \
    q5 = *(const float2*)(bp + 5 * ldb);                         \
    q6 = *(const float2*)(bp + 6 * ldb);                         \
    q7 = *(const float2*)(bp + 7 * ldb);                         \
  }

#define STORE_B()                                                              \
  if (BSTAGE == 0) {                                                           \
    if (BSCL) { t0 *= inv; t1 *= inv; t2 *= inv; t3 *= inv; }                  \
    if (BRSCL) { t0 *= rscl; t1 *= rscl; t2 *= rscl; t3 *= rscl; }             \
    split8_h(t0, t1, Bs + oB0, 4096);                                          \
    split8_h(t2, t3, Bs + oB1, 4096);                                          \
  } else {                                                                     \
    if (BSCL) {                                                                \
      q0.x *= inv; q0.y *= inv; q1.x *= inv; q1.y *= inv;                      \
      q2.x *= inv; q2.y *= inv; q3.x *= inv; q3.y *= inv;                      \
      q4.x *= inv; q4.y *= inv; q5.x *= inv; q5.y *= inv;                      \
      q6.x *= inv; q6.y *= inv; q7.x *= inv; q7.y *= inv;                      \
    }                                                                          \
    split8v(q0.x, q1.x, q2.x, q3.x, q4.x, q5.x, q6.x, q7.x, Bs + oB0, 4096);   \
    split8v(q0.y, q1.y, q2.y, q3.y, q4.y, q5.y, q6.y, q7.y, Bs + oB1, 4096);   \
  }

  LOAD_A(0)
  LOAD_B(0)
  STORE_A()
  STORE_B()
  __syncthreads();

  for (int k0 = 0; k0 < K; k0 += 32) {
    bool more = (k0 + 32) < K;
    if (more) {
      LOAD_A(k0 + 32)
      LOAD_B(k0 + 32)
    }
    f16x8 ah[4], bh[4];
#pragma unroll
    for (int mi = 0; mi < 4; mi++)
      ah[mi] = ldfrag(As + swzB(wm * 64 + mi * 16 + lr, lg));
#pragma unroll
    for (int ni = 0; ni < 4; ni++)
      bh[ni] = ldfrag(Bs + swzB(wn * 64 + ni * 16 + lr, lg));
#pragma unroll
    for (int ni = 0; ni < 4; ni++)
#pragma unroll
      for (int mi = 0; mi < 4; mi++)
        acc[mi][ni] = __builtin_amdgcn_mfma_f32_16x16x32_f16(
            ah[mi], bh[ni], acc[mi][ni], 0, 0, 0);
    {
      f16x8 bm[4];
#pragma unroll
      for (int ni = 0; ni < 4; ni++)
        bm[ni] = ldfrag(Bs + 4096 + swzB(wn * 64 + ni * 16 + lr, lg));
#pragma unroll
      for (int ni = 0; ni < 4; ni++)
#pragma unroll
        for (int mi = 0; mi < 4; mi++)
          acc[mi][ni] = __builtin_amdgcn_mfma_f32_16x16x32_f16(
              ah[mi], bm[ni], acc[mi][ni], 0, 0, 0);
    }
    {
      f16x8 am[4];
#pragma unroll
      for (int mi = 0; mi < 4; mi++)
        am[mi] = ldfrag(As + 4096 + swzB(wm * 64 + mi * 16 + lr, lg));
#pragma unroll
      for (int ni = 0; ni < 4; ni++)
#pragma unroll
        for (int mi = 0; mi < 4; mi++)
          acc[mi][ni] = __builtin_amdgcn_mfma_f32_16x16x32_f16(
              am[mi], bh[ni], acc[mi][ni], 0, 0, 0);
    }
    __syncthreads();
    if (more) {
      STORE_A()
      STORE_B()
    }
    __syncthreads();
  }

  const size_t cb = (size_t)b * sC;
  float invs = 0.f;
  if (MODE == 2) invs = 1.0f / sqrtf(trv[b] + EPSV);
#pragma unroll
  for (int mi = 0; mi < 4; mi++)
#pragma unroll
    for (int ni = 0; ni < 4; ni++)
#pragma unroll
      for (int j = 0; j < 4; j++) {
        int rowc = m0 + wm * 64 + mi * 16 + lg * 4 + j;
        int colc = n0 + wn * 64 + ni * 16 + lr;
        float v = acc[mi][ni][j];
        if (MODE == 0) {
          float o = alpha * v;
          if (rowc == colc) o += diagAdd;
          pC[cb + (size_t)rowc * 384 + colc] = o;
        } else if (MODE == 1) {
          size_t ix = cb + (size_t)rowc * 384 + colc;
          float mn = pMn[ix] * inv;
          float p1 = pP1[ix];
          float y2 = -1.875f * mn + 0.75f * p1 - 0.125f * v;
          if (rowc == colc) y2 += 2.25f;
          pC[ix] = y2;
        } else {
          if (colc >= rowc) {
            long idx = (long)b * SID + (long)rowc * 384 -
                       (long)rowc * (rowc - 1) / 2 + (colc - rowc);
            pC[idx] = alpha * v * invs;
          }
        }
      }
#undef LOAD_A
#undef STORE_A
#undef LOAD_B
#undef STORE_B
}

// ---------------- FC: part[kc] = V @ W2 (320-k chunk, 924 blocks) -----------
#define FC_NCH 231

__global__ __launch_bounds__(256, 4) void k_fc(const float* __restrict__ V,
                                               const float* __restrict__ W2,
                                               float* __restrict__ part) {
  __shared__ short As[2 * 64 * 32];
  __shared__ short Bs[2 * 128 * 32];
  int n0 = blockIdx.x * 128;
  int kc = blockIdx.y;
  int tid = threadIdx.x;
  int lane = tid & 63, wid = tid >> 6;
  int wm = wid >> 1, wn = wid & 1;
  int lr = lane & 15, lg = lane >> 4;
  int rowA = tid >> 2, subA = tid & 3;
  int oA = swzB(rowA, subA);
  int nB = tid >> 1, kh = tid & 1;
  int oB0 = swzB(nB, 2 * kh), oB1 = swzB(nB, 2 * kh + 1);
  const float* Aptr = V + (size_t)rowA * SID + kc * 320 + subA * 8;
  const float* Bptr = W2 + (size_t)(kc * 320 + kh * 16) * DOUT + n0 + nB;
  f32x4 acc[2][4] = {};
  f32x4 a0, a1, w0, w1, w2, w3;

#define FC_LOADB(off)                                                       \
  {                                                                         \
    const float* bp = Bptr + (size_t)(off) * DOUT;                          \
    w0[0] = bp[0 * DOUT];  w0[1] = bp[1 * DOUT];                            \
    w0[2] = bp[2 * DOUT];  w0[3] = bp[3 * DOUT];                            \
    w1[0] = bp[4 * DOUT];  w1[1] = bp[5 * DOUT];                            \
    w1[2] = bp[6 * DOUT];  w1[3] = bp[7 * DOUT];                            \
    w2[0] = bp[8 * DOUT];  w2[1] = bp[9 * DOUT];                            \
    w2[2] = bp[10 * DOUT]; w2[3] = bp[11 * DOUT];                           \
    w3[0] = bp[12 * DOUT]; w3[1] = bp[13 * DOUT];                           \
    w3[2] = bp[14 * DOUT]; w3[3] = bp[15 * DOUT];                           \
  }

  a0 = *(const f32x4*)(Aptr + 0);
  a1 = *(const f32x4*)(Aptr + 4);
  FC_LOADB(0);
  split8_h(a0, a1, As + oA, 2048);
  split8_h(w0, w1, Bs + oB0, 4096);
  split8_h(w2, w3, Bs + oB1, 4096);
  __syncthreads();

  for (int st = 0; st < 10; st++) {
    bool more = st < 9;
    if (more) {
      a0 = *(const f32x4*)(Aptr + (st + 1) * 32);
      a1 = *(const f32x4*)(Aptr + (st + 1) * 32 + 4);
      FC_LOADB((st + 1) * 32);
    }
#pragma unroll
    for (int ib = 0; ib < 2; ib++) {
      f16x8 bfr[4];
#pragma unroll
      for (int ni = 0; ni < 4; ni++)
        bfr[ni] = ldfrag(Bs + ib * 4096 + swzB(wn * 64 + ni * 16 + lr, lg));
#pragma unroll
      for (int ia = 0; ia < 2; ia++) {
        if (ia + ib > 1) continue;
        f16x8 afr[2];
#pragma unroll
        for (int mi = 0; mi < 2; mi++)
          afr[mi] = ldfrag(As + ia * 2048 + swzB(wm * 32 + mi * 16 + lr, lg));
#pragma unroll
        for (int ni = 0; ni < 4; ni++)
#pragma unroll
          for (int mi = 0; mi < 2; mi++)
            acc[mi][ni] = __builtin_amdgcn_mfma_f32_16x16x32_f16(
                afr[mi], bfr[ni], acc[mi][ni], 0, 0, 0);
      }
    }
    __syncthreads();
    if (more) {
      split8_h(a0, a1, As + oA, 2048);
      split8_h(w0, w1, Bs + oB0, 4096);
      split8_h(w2, w3, Bs + oB1, 4096);
    }
    __syncthreads();
  }

  float* p = part + (size_t)kc * (BB * DOUT) + n0;
#pragma unroll
  for (int mi = 0; mi < 2; mi++)
#pragma unroll
    for (int ni = 0; ni < 4; ni++)
#pragma unroll
      for (int j = 0; j < 4; j++)
        p[(size_t)(wm * 32 + mi * 16 + lg * 4 + j) * DOUT + wn * 64 + ni * 16 + lr] =
            acc[mi][ni][j];
}

__global__ __launch_bounds__(256) void k_reduce(const float* __restrict__ part,
                                                const float* __restrict__ b2,
                                                float* __restrict__ out) {
  int idx = blockIdx.x * 256 + threadIdx.x;
  int c = idx & (DOUT - 1);
  float s = 0.f;
  for (int kc = 0; kc < FC_NCH; kc++) s += part[(size_t)kc * BB * DOUT + idx];
  float x = s + b2[c];
  out[idx] = 0.5f * x * (1.0f + erff(x * 0.70710678118654752f));
}

// ---------------- launch ----------------

extern "C" void kernel_launch(void* const* d_in, const int* in_sizes, int n_in,
                              void* d_out, int out_size, void* d_ws, size_t ws_size,
                              hipStream_t stream) {
  (void)in_sizes; (void)n_in; (void)out_size; (void)ws_size;
  const float* tokens = (const float*)d_in[0];
  const float* graph = (const float*)d_in[1];
  const float* W2 = (const float*)d_in[2];
  const float* b2 = (const float*)d_in[3];

  float* ws = (float*)d_ws;
  const long NM = 9437184L;
  float* s1 = ws + NM;        // ZT
  float* s2 = ws + 2 * NM;    // WZT (ld 384)
  float* s3 = ws + 3 * NM;    // M2 (raw, unscaled)
  float* s4 = ws + 4 * NM;    // P1
  float* s5 = ws + 5 * NM;    // Y2
  float* s6 = ws + 6 * NM;    // T
  float* s7 = ws + 7 * NM;    // V (packed triu)
  float* s8 = ws + 8 * NM;    // part
  float* colw = ws + 9 * NM;
  float* wmv = colw + BB * NSEQ;
  float* trv = wmv + BB * DI;
  float* colwp = trv + BB;              // 8*64*256 partials
  float* wmp = colwp + 8 * BB * NSEQ;   // 8*64*384 partials
  float* ivd = wmp + 8 * BB * DI;       // 64*256 inv-degrees

  k_deg<<<(BB * NSEQ) / 4, 256, 0, stream>>>(graph, ivd);
  k_colw1<<<dim3(BB, 8), 256, 0, stream>>>(graph, ivd, colwp);
  k_colw2<<<BB, 256, 0, stream>>>(colwp, colw);
  k_wmean1<<<dim3(BB, 8), 384, 0, stream>>>(colw, tokens, wmp);
  k_wmean2<<<(BB * DI) / 256, 256, 0, stream>>>(wmp, wmv);
  k_zcT<<<dim3(6, 4, BB), 256, 0, stream>>>(tokens, wmv, s1);

  // WZT[e][n] = sum_k ZT[e][k] * (graph[n][k]*ivd[n])  (NT + BRSCL) -> s2
  gemm_k<0, 0, 0, 0, 1><<<6 * BB, 256, 0, stream>>>(
      s1, graph, s2, nullptr, nullptr, nullptr, ivd, 256, 256, 256,
      98304L, 65536L, 147456L, 1.f, 0.f, 2, 6);
  // M2[d][e] = sum_n ZT[d][n] WZT[e][n]  (NT; M=N=384,K=256) -> s3
  gemm_k<0, 0, 0, 0, 0><<<9 * BB, 256, 0, stream>>>(
      s1, s2, s3, nullptr, nullptr, nullptr, nullptr, 256, 256, 384,
      98304L, 147456L, 147456L, 1.f, 0.f, 3, 9);

  k_trace<<<BB, 256, 0, stream>>>(s3, trv);

  // P1 = NN(M2*inv, M2*inv) -> s4
  gemm_k<0, 1, 1, 1, 0><<<9 * BB, 256, 0, stream>>>(
      s3, s3, s4, nullptr, nullptr, trv, nullptr, 384, 384, 384,
      147456L, 147456L, 147456L, 1.f, 0.f, 3, 9);
  // H = NN(M2*inv, P1); Y2 epilogue -> s5
  gemm_k<1, 1, 1, 0, 0><<<9 * BB, 256, 0, stream>>>(
      s3, s4, s5, s3, s4, trv, nullptr, 384, 384, 384,
      147456L, 147456L, 147456L, 0.f, 0.f, 3, 9);
  // T = 3I - NN(M2*inv, Y2) -> s6
  gemm_k<0, 1, 1, 0, 0><<<9 * BB, 256, 0, stream>>>(
      s3, s5, s6, nullptr, nullptr, trv, nullptr, 384, 384, 384,
      147456L, 147456L, 147456L, -1.f, 3.f, 3, 9);
  // V = triu(0.5 * NN(Y2, T)) / sqrt(tr+eps) -> s7 (packed)
  gemm_k<2, 1, 0, 0, 0><<<9 * BB, 256, 0, stream>>>(
      s5, s6, s7, nullptr, nullptr, trv, nullptr, 384, 384, 384,
      147456L, 147456L, 0L, 0.5f, 0.f, 3, 9);

  // part[kc] = V @ W2 chunk; then out = gelu(sum + b2)
  k_fc<<<dim3(4, FC_NCH), 256, 0, stream>>>(s7, W2, s8);
  k_reduce<<<(BB * DOUT) / 256, 256, 0, stream>>>(s8, b2, (float*)d_out);
}

// Round 18
// 287.048 us; speedup vs baseline: 2.8414x; 2.8414x over previous
//
#include <hip/hip_runtime.h>
#include <hip/hip_fp16.h>
#include <math.h>

#define DI 384
#define NSEQ 256
#define BB 64
#define DOUT 512
#define SID 73920
#define EPSV 1e-5f

typedef float f32x4 __attribute__((ext_vector_type(4)));
typedef short s16x8 __attribute__((ext_vector_type(8)));
typedef _Float16 f16x8 __attribute__((ext_vector_type(8)));

// ---------------- small kernels ----------------

// invdeg[b][n] = 1/(sum_k graph[b][n][k] + eps); one wave per row, coalesced.
__global__ __launch_bounds__(256) void k_deg(const float* __restrict__ graph,
                                             float* __restrict__ ivd) {
  int row = blockIdx.x * 4 + (threadIdx.x >> 6);  // 16384 rows
  int l = threadIdx.x & 63;
  const float* g = graph + (size_t)row * NSEQ;
  float s = g[l] + g[l + 64] + g[l + 128] + g[l + 192];
#pragma unroll
  for (int o = 32; o > 0; o >>= 1) s += __shfl_down(s, o);
  if (l == 0) ivd[row] = 1.0f / (s + EPSV);
}

// colw 2-stage over weights = graph * invdeg (computed on the fly)
__global__ __launch_bounds__(256) void k_colw1(const float* __restrict__ graph,
                                               const float* __restrict__ ivd,
                                               float* __restrict__ part) {
  int b = blockIdx.x, nc = blockIdx.y;
  int j = threadIdx.x;
  const float* g = graph + (size_t)b * NSEQ * NSEQ + (size_t)nc * 32 * NSEQ + j;
  const float* iv = ivd + b * NSEQ + nc * 32;
  float s = 0.f;
#pragma unroll
  for (int n = 0; n < 32; n++) s += g[(size_t)n * NSEQ] * iv[n];
  part[((size_t)nc * BB + b) * NSEQ + j] = s;
}

__global__ __launch_bounds__(256) void k_colw2(const float* __restrict__ part,
                                               float* __restrict__ colw) {
  int idx = blockIdx.x * 256 + threadIdx.x;  // 64*256
  float s = 0.f;
#pragma unroll
  for (int nc = 0; nc < 8; nc++) s += part[(size_t)nc * BB * NSEQ + idx];
  colw[idx] = s;
}

// wmean 2-stage: wm[b][d] = sum_n colw[b][n]*tokens[b][n][d]
__global__ __launch_bounds__(384) void k_wmean1(const float* __restrict__ colw,
                                                const float* __restrict__ tokens,
                                                float* __restrict__ part) {
  int b = blockIdx.x, nc = blockIdx.y;
  int d = threadIdx.x;
  const float* t = tokens + (size_t)b * NSEQ * DI + (size_t)nc * 32 * DI + d;
  const float* cw = colw + b * NSEQ + nc * 32;
  float s = 0.f;
#pragma unroll
  for (int n = 0; n < 32; n++) s += cw[n] * t[(size_t)n * DI];
  part[((size_t)nc * BB + b) * DI + d] = s;
}

__global__ __launch_bounds__(256) void k_wmean2(const float* __restrict__ part,
                                                float* __restrict__ wm) {
  int idx = blockIdx.x * 256 + threadIdx.x;  // 64*384
  float s = 0.f;
#pragma unroll
  for (int nc = 0; nc < 8; nc++) s += part[(size_t)nc * BB * DI + idx];
  wm[idx] = s;
}

// ZT[b][d][n] = tokens[b][n][d] - wm[b][d]
__global__ __launch_bounds__(256) void k_zcT(const float* __restrict__ tokens,
                                             const float* __restrict__ wm,
                                             float* __restrict__ ZT) {
  int b = blockIdx.z;
  int d0 = blockIdx.x * 64, n0 = blockIdx.y * 64;
  __shared__ float ld[64][68];
  const float* Tb = tokens + (size_t)b * NSEQ * DI;
  const float* wmb = wm + (size_t)b * DI;
  float* Zb = ZT + (size_t)b * DI * NSEQ;
#pragma unroll
  for (int i = 0; i < 4; i++) {
    int sl = threadIdx.x + i * 256;
    int r = sl >> 4, q = sl & 15;
    float4 v = *(const float4*)&Tb[(size_t)(n0 + r) * DI + d0 + q * 4];
    float4 m = *(const float4*)&wmb[d0 + q * 4];
    v.x -= m.x; v.y -= m.y; v.z -= m.z; v.w -= m.w;
    *(float4*)&ld[r][q * 4] = v;
  }
  __syncthreads();
#pragma unroll
  for (int i = 0; i < 4; i++) {
    int sl = threadIdx.x + i * 256;
    int dl = sl >> 4, q = sl & 15;
    float4 v;
    v.x = ld[q * 4 + 0][dl];
    v.y = ld[q * 4 + 1][dl];
    v.z = ld[q * 4 + 2][dl];
    v.w = ld[q * 4 + 3][dl];
    *(float4*)&Zb[(size_t)(d0 + dl) * NSEQ + n0 + q * 4] = v;
  }
}

__global__ __launch_bounds__(256) void k_trace(const float* __restrict__ M2,
                                               float* __restrict__ tr) {
  int b = blockIdx.x;
  int t = threadIdx.x;
  float s = 0.f;
  for (int d = t; d < DI; d += 256)
    s += M2[(size_t)b * DI * DI + (size_t)d * DI + d];
  __shared__ float red[256];
  red[t] = s;
  __syncthreads();
  for (int st = 128; st > 0; st >>= 1) {
    if (t < st) red[t] += red[t + st];
    __syncthreads();
  }
  if (t == 0) tr[b] = red[0];
}

// ---------------- fp16 2-plane split helpers --------------------------------

__device__ __forceinline__ int swzB(int row, int s) {
  return (((row << 2) + s) ^ ((row >> 1) & 7)) << 3;  // in shorts
}

__device__ __forceinline__ unsigned splitpair_h(float a, float c, float& ra,
                                                float& rc) {
  __half2 h = __float22half2_rn(make_float2(a, c));
  unsigned u;
  __builtin_memcpy(&u, &h, 4);
  ra = a - __low2float(h);
  rc = c - __high2float(h);
  return u;
}

__device__ __forceinline__ unsigned packh2(float a, float c) {
  __half2 h = __float22half2_rn(make_float2(a, c));
  unsigned u;
  __builtin_memcpy(&u, &h, 4);
  return u;
}

__device__ __forceinline__ void split8v(float x0, float x1, float x2, float x3,
                                        float x4, float x5, float x6, float x7,
                                        short* dst, int ps) {
  unsigned h0, h1, h2, h3, m0, m1, m2, m3;
  float ra, rc;
  h0 = splitpair_h(x0, x1, ra, rc); m0 = packh2(ra, rc);
  h1 = splitpair_h(x2, x3, ra, rc); m1 = packh2(ra, rc);
  h2 = splitpair_h(x4, x5, ra, rc); m2 = packh2(ra, rc);
  h3 = splitpair_h(x6, x7, ra, rc); m3 = packh2(ra, rc);
  uint4 H, M;
  H.x = h0; H.y = h1; H.z = h2; H.w = h3;
  M.x = m0; M.y = m1; M.z = m2; M.w = m3;
  *(uint4*)(dst) = H;
  *(uint4*)(dst + ps) = M;
}

__device__ __forceinline__ void split8_h(f32x4 v0, f32x4 v1, short* dst, int ps) {
  split8v(v0[0], v0[1], v0[2], v0[3], v1[0], v1[1], v1[2], v1[3], dst, ps);
}

__device__ __forceinline__ f16x8 ldfrag(const short* p) {
  s16x8 t = *(const s16x8*)p;
  return __builtin_bit_cast(f16x8, t);
}

// ---------------- fp16-split MFMA GEMM --------------------------------------
// (256,3): occupancy optimum. r16: (256,2) leaves a 64-block serialized tail
// (288->328 us); r17: (256,4) spills (VGPR_Count 64, WRITE_SIZE 10x, 816 us).
template <int MODE, int BSTAGE, int ASCL, int BSCL, int BRSCL>
__global__ __launch_bounds__(256, 3) void gemm_k(
    const float* __restrict__ pA, const float* __restrict__ pB,
    float* __restrict__ pC, const float* __restrict__ pMn,
    const float* __restrict__ pP1, const float* __restrict__ trv,
    const float* __restrict__ pRScl, int K, int lda, int ldb, long sA, long sB,
    long sC, float alpha, float diagAdd, int ntn, int ntile) {
  __shared__ short As[2 * 128 * 32];
  __shared__ short Bs[2 * 128 * 32];
  int flat = blockIdx.x;
  int q = flat >> 3;
  int b = (flat & 7) + (q / ntile) * 8;
  int tk = q % ntile;
  int m0 = (tk / ntn) * 128;
  int n0 = (tk % ntn) * 128;
  int tid = threadIdx.x;
  int lane = tid & 63, wid = tid >> 6;
  int wm = wid >> 1, wn = wid & 1;
  int lr = lane & 15, lg = lane >> 4;
  float inv = 0.f;
  if (ASCL || BSCL || MODE == 1) inv = 1.0f / (trv[b] + EPSV);

  int rowA = tid >> 1, subA = tid & 1;
  int oA0 = swzB(rowA, 2 * subA), oA1 = swzB(rowA, 2 * subA + 1);
  const float* Aptr = pA + (size_t)b * sA + (size_t)(m0 + rowA) * lda + subA * 16;

  int rowB = tid >> 1;
  const float* Bptr;
  int oB0, oB1;
  float rscl = 1.f;
  if (BSTAGE == 0) {
    int subB = tid & 1;
    oB0 = swzB(rowB, 2 * subB);
    oB1 = swzB(rowB, 2 * subB + 1);
    Bptr = pB + (size_t)b * sB + (size_t)(n0 + rowB) * ldb + subB * 16;
    if (BRSCL) rscl = pRScl[(size_t)b * NSEQ + n0 + rowB];
  } else {
    int nB = (tid & 63) * 2, kk8 = (tid >> 6) * 8;
    oB0 = swzB(nB, kk8 >> 3);
    oB1 = swzB(nB + 1, kk8 >> 3);
    Bptr = pB + (size_t)b * sB + (size_t)kk8 * ldb + n0 + nB;
  }

  f32x4 acc[4][4] = {};
  f32x4 a0, a1, a2, a3;
  f32x4 t0, t1, t2, t3;
  float2 q0, q1, q2, q3, q4, q5, q6, q7;

#define LOAD_A(OFF)                      \
  a0 = *(const f32x4*)(Aptr + (OFF));    \
  a1 = *(const f32x4*)(Aptr + (OFF) + 4);\
  a2 = *(const f32x4*)(Aptr + (OFF) + 8);\
  a3 = *(const f32x4*)(Aptr + (OFF) + 12);

#define STORE_A()                                            \
  {                                                          \
    if (ASCL) { a0 *= inv; a1 *= inv; a2 *= inv; a3 *= inv; }\
    split8_h(a0, a1, As + oA0, 4096);                        \
    split8_h(a2, a3, As + oA1, 4096);                        \
  }

#define LOAD_B(OFF)                                              \
  if (BSTAGE == 0) {                                             \
    t0 = *(const f32x4*)(Bptr + (OFF));                          \
    t1 = *(const f32x4*)(Bptr + (OFF) + 4);                      \
    t2 = *(const f32x4*)(Bptr + (OFF) + 8);                      \
    t3 = *(const f32x4*)(Bptr + (OFF) + 12);                     \
  } else {                                                       \
    const float* bp = Bptr + (size_t)(OFF) * ldb;                \
    q0 = *(const float2*)(bp);                                   \
    q1 = *(const float2*)(bp + ldb);                             \
    q2 = *(const float2*)(bp + 2 * ldb);                         \
    q3 = *(const float2*)(bp + 3 * ldb);                         \
    q4 = *(const float2*)(bp + 4 * ldb);                         \
    q5 = *(const float2*)(bp + 5 * ldb);                         \
    q6 = *(const float2*)(bp + 6 * ldb);                         \
    q7 = *(const float2*)(bp + 7 * ldb);                         \
  }

#define STORE_B()                                                              \
  if (BSTAGE == 0) {                                                           \
    if (BSCL) { t0 *= inv; t1 *= inv; t2 *= inv; t3 *= inv; }                  \
    if (BRSCL) { t0 *= rscl; t1 *= rscl; t2 *= rscl; t3 *= rscl; }             \
    split8_h(t0, t1, Bs + oB0, 4096);                                          \
    split8_h(t2, t3, Bs + oB1, 4096);                                          \
  } else {                                                                     \
    if (BSCL) {                                                                \
      q0.x *= inv; q0.y *= inv; q1.x *= inv; q1.y *= inv;                      \
      q2.x *= inv; q2.y *= inv; q3.x *= inv; q3.y *= inv;                      \
      q4.x *= inv; q4.y *= inv; q5.x *= inv; q5.y *= inv;                      \
      q6.x *= inv; q6.y *= inv; q7.x *= inv; q7.y *= inv;                      \
    }                                                                          \
    split8v(q0.x, q1.x, q2.x, q3.x, q4.x, q5.x, q6.x, q7.x, Bs + oB0, 4096);   \
    split8v(q0.y, q1.y, q2.y, q3.y, q4.y, q5.y, q6.y, q7.y, Bs + oB1, 4096);   \
  }

  LOAD_A(0)
  LOAD_B(0)
  STORE_A()
  STORE_B()
  __syncthreads();

  for (int k0 = 0; k0 < K; k0 += 32) {
    bool more = (k0 + 32) < K;
    if (more) {
      LOAD_A(k0 + 32)
      LOAD_B(k0 + 32)
    }
    f16x8 ah[4], bh[4];
#pragma unroll
    for (int mi = 0; mi < 4; mi++)
      ah[mi] = ldfrag(As + swzB(wm * 64 + mi * 16 + lr, lg));
#pragma unroll
    for (int ni = 0; ni < 4; ni++)
      bh[ni] = ldfrag(Bs + swzB(wn * 64 + ni * 16 + lr, lg));
#pragma unroll
    for (int ni = 0; ni < 4; ni++)
#pragma unroll
      for (int mi = 0; mi < 4; mi++)
        acc[mi][ni] = __builtin_amdgcn_mfma_f32_16x16x32_f16(
            ah[mi], bh[ni], acc[mi][ni], 0, 0, 0);
    {
      f16x8 bm[4];
#pragma unroll
      for (int ni = 0; ni < 4; ni++)
        bm[ni] = ldfrag(Bs + 4096 + swzB(wn * 64 + ni * 16 + lr, lg));
#pragma unroll
      for (int ni = 0; ni < 4; ni++)
#pragma unroll
        for (int mi = 0; mi < 4; mi++)
          acc[mi][ni] = __builtin_amdgcn_mfma_f32_16x16x32_f16(
              ah[mi], bm[ni], acc[mi][ni], 0, 0, 0);
    }
    {
      f16x8 am[4];
#pragma unroll
      for (int mi = 0; mi < 4; mi++)
        am[mi] = ldfrag(As + 4096 + swzB(wm * 64 + mi * 16 + lr, lg));
#pragma unroll
      for (int ni = 0; ni < 4; ni++)
#pragma unroll
        for (int mi = 0; mi < 4; mi++)
          acc[mi][ni] = __builtin_amdgcn_mfma_f32_16x16x32_f16(
              am[mi], bh[ni], acc[mi][ni], 0, 0, 0);
    }
    __syncthreads();
    if (more) {
      STORE_A()
      STORE_B()
    }
    __syncthreads();
  }

  const size_t cb = (size_t)b * sC;
  float invs = 0.f;
  if (MODE == 2) invs = 1.0f / sqrtf(trv[b] + EPSV);
#pragma unroll
  for (int mi = 0; mi < 4; mi++)
#pragma unroll
    for (int ni = 0; ni < 4; ni++)
#pragma unroll
      for (int j = 0; j < 4; j++) {
        int rowc = m0 + wm * 64 + mi * 16 + lg * 4 + j;
        int colc = n0 + wn * 64 + ni * 16 + lr;
        float v = acc[mi][ni][j];
        if (MODE == 0) {
          float o = alpha * v;
          if (rowc == colc) o += diagAdd;
          pC[cb + (size_t)rowc * 384 + colc] = o;
        } else if (MODE == 1) {
          size_t ix = cb + (size_t)rowc * 384 + colc;
          float mn = pMn[ix] * inv;
          float p1 = pP1[ix];
          float y2 = -1.875f * mn + 0.75f * p1 - 0.125f * v;
          if (rowc == colc) y2 += 2.25f;
          pC[ix] = y2;
        } else {
          if (colc >= rowc) {
            long idx = (long)b * SID + (long)rowc * 384 -
                       (long)rowc * (rowc - 1) / 2 + (colc - rowc);
            pC[idx] = alpha * v * invs;
          }
        }
      }
#undef LOAD_A
#undef STORE_A
#undef LOAD_B
#undef STORE_B
}

// ---------------- FC: part[kc] = V @ W2 (320-k chunk, 924 blocks) -----------
#define FC_NCH 231

__global__ __launch_bounds__(256, 3) void k_fc(const float* __restrict__ V,
                                               const float* __restrict__ W2,
                                               float* __restrict__ part) {
  __shared__ short As[2 * 64 * 32];
  __shared__ short Bs[2 * 128 * 32];
  int n0 = blockIdx.x * 128;
  int kc = blockIdx.y;
  int tid = threadIdx.x;
  int lane = tid & 63, wid = tid >> 6;
  int wm = wid >> 1, wn = wid & 1;
  int lr = lane & 15, lg = lane >> 4;
  int rowA = tid >> 2, subA = tid & 3;
  int oA = swzB(rowA, subA);
  int nB = tid >> 1, kh = tid & 1;
  int oB0 = swzB(nB, 2 * kh), oB1 = swzB(nB, 2 * kh + 1);
  const float* Aptr = V + (size_t)rowA * SID + kc * 320 + subA * 8;
  const float* Bptr = W2 + (size_t)(kc * 320 + kh * 16) * DOUT + n0 + nB;
  f32x4 acc[2][4] = {};
  f32x4 a0, a1, w0, w1, w2, w3;

#define FC_LOADB(off)                                                       \
  {                                                                         \
    const float* bp = Bptr + (size_t)(off) * DOUT;                          \
    w0[0] = bp[0 * DOUT];  w0[1] = bp[1 * DOUT];                            \
    w0[2] = bp[2 * DOUT];  w0[3] = bp[3 * DOUT];                            \
    w1[0] = bp[4 * DOUT];  w1[1] = bp[5 * DOUT];                            \
    w1[2] = bp[6 * DOUT];  w1[3] = bp[7 * DOUT];                            \
    w2[0] = bp[8 * DOUT];  w2[1] = bp[9 * DOUT];                            \
    w2[2] = bp[10 * DOUT]; w2[3] = bp[11 * DOUT];                           \
    w3[0] = bp[12 * DOUT]; w3[1] = bp[13 * DOUT];                           \
    w3[2] = bp[14 * DOUT]; w3[3] = bp[15 * DOUT];                           \
  }

  a0 = *(const f32x4*)(Aptr + 0);
  a1 = *(const f32x4*)(Aptr + 4);
  FC_LOADB(0);
  split8_h(a0, a1, As + oA, 2048);
  split8_h(w0, w1, Bs + oB0, 4096);
  split8_h(w2, w3, Bs + oB1, 4096);
  __syncthreads();

  for (int st = 0; st < 10; st++) {
    bool more = st < 9;
    if (more) {
      a0 = *(const f32x4*)(Aptr + (st + 1) * 32);
      a1 = *(const f32x4*)(Aptr + (st + 1) * 32 + 4);
      FC_LOADB((st + 1) * 32);
    }
#pragma unroll
    for (int ib = 0; ib < 2; ib++) {
      f16x8 bfr[4];
#pragma unroll
      for (int ni = 0; ni < 4; ni++)
        bfr[ni] = ldfrag(Bs + ib * 4096 + swzB(wn * 64 + ni * 16 + lr, lg));
#pragma unroll
      for (int ia = 0; ia < 2; ia++) {
        if (ia + ib > 1) continue;
        f16x8 afr[2];
#pragma unroll
        for (int mi = 0; mi < 2; mi++)
          afr[mi] = ldfrag(As + ia * 2048 + swzB(wm * 32 + mi * 16 + lr, lg));
#pragma unroll
        for (int ni = 0; ni < 4; ni++)
#pragma unroll
          for (int mi = 0; mi < 2; mi++)
            acc[mi][ni] = __builtin_amdgcn_mfma_f32_16x16x32_f16(
                afr[mi], bfr[ni], acc[mi][ni], 0, 0, 0);
      }
    }
    __syncthreads();
    if (more) {
      split8_h(a0, a1, As + oA, 2048);
      split8_h(w0, w1, Bs + oB0, 4096);
      split8_h(w2, w3, Bs + oB1, 4096);
    }
    __syncthreads();
  }

  float* p = part + (size_t)kc * (BB * DOUT) + n0;
#pragma unroll
  for (int mi = 0; mi < 2; mi++)
#pragma unroll
    for (int ni = 0; ni < 4; ni++)
#pragma unroll
      for (int j = 0; j < 4; j++)
        p[(size_t)(wm * 32 + mi * 16 + lg * 4 + j) * DOUT + wn * 64 + ni * 16 + lr] =
            acc[mi][ni][j];
}

__global__ __launch_bounds__(256) void k_reduce(const float* __restrict__ part,
                                                const float* __restrict__ b2,
                                                float* __restrict__ out) {
  int idx = blockIdx.x * 256 + threadIdx.x;
  int c = idx & (DOUT - 1);
  float s = 0.f;
  for (int kc = 0; kc < FC_NCH; kc++) s += part[(size_t)kc * BB * DOUT + idx];
  float x = s + b2[c];
  out[idx] = 0.5f * x * (1.0f + erff(x * 0.70710678118654752f));
}

// ---------------- launch ----------------

extern "C" void kernel_launch(void* const* d_in, const int* in_sizes, int n_in,
                              void* d_out, int out_size, void* d_ws, size_t ws_size,
                              hipStream_t stream) {
  (void)in_sizes; (void)n_in; (void)out_size; (void)ws_size;
  const float* tokens = (const float*)d_in[0];
  const float* graph = (const float*)d_in[1];
  const float* W2 = (const float*)d_in[2];
  const float* b2 = (const float*)d_in[3];

  float* ws = (float*)d_ws;
  const long NM = 9437184L;
  float* s1 = ws + NM;        // ZT
  float* s2 = ws + 2 * NM;    // WZT (ld 384)
  float* s3 = ws + 3 * NM;    // M2 (raw, unscaled)
  float* s4 = ws + 4 * NM;    // P1
  float* s5 = ws + 5 * NM;    // Y2
  float* s6 = ws + 6 * NM;    // T
  float* s7 = ws + 7 * NM;    // V (packed triu)
  float* s8 = ws + 8 * NM;    // part
  float* colw = ws + 9 * NM;
  float* wmv = colw + BB * NSEQ;
  float* trv = wmv + BB * DI;
  float* colwp = trv + BB;              // 8*64*256 partials
  float* wmp = colwp + 8 * BB * NSEQ;   // 8*64*384 partials
  float* ivd = wmp + 8 * BB * DI;       // 64*256 inv-degrees

  k_deg<<<(BB * NSEQ) / 4, 256, 0, stream>>>(graph, ivd);
  k_colw1<<<dim3(BB, 8), 256, 0, stream>>>(graph, ivd, colwp);
  k_colw2<<<BB, 256, 0, stream>>>(colwp, colw);
  k_wmean1<<<dim3(BB, 8), 384, 0, stream>>>(colw, tokens, wmp);
  k_wmean2<<<(BB * DI) / 256, 256, 0, stream>>>(wmp, wmv);
  k_zcT<<<dim3(6, 4, BB), 256, 0, stream>>>(tokens, wmv, s1);

  // WZT[e][n] = sum_k ZT[e][k] * (graph[n][k]*ivd[n])  (NT + BRSCL) -> s2
  gemm_k<0, 0, 0, 0, 1><<<6 * BB, 256, 0, stream>>>(
      s1, graph, s2, nullptr, nullptr, nullptr, ivd, 256, 256, 256,
      98304L, 65536L, 147456L, 1.f, 0.f, 2, 6);
  // M2[d][e] = sum_n ZT[d][n] WZT[e][n]  (NT; M=N=384,K=256) -> s3
  gemm_k<0, 0, 0, 0, 0><<<9 * BB, 256, 0, stream>>>(
      s1, s2, s3, nullptr, nullptr, nullptr, nullptr, 256, 256, 384,
      98304L, 147456L, 147456L, 1.f, 0.f, 3, 9);

  k_trace<<<BB, 256, 0, stream>>>(s3, trv);

  // P1 = NN(M2*inv, M2*inv) -> s4
  gemm_k<0, 1, 1, 1, 0><<<9 * BB, 256, 0, stream>>>(
      s3, s3, s4, nullptr, nullptr, trv, nullptr, 384, 384, 384,
      147456L, 147456L, 147456L, 1.f, 0.f, 3, 9);
  // H = NN(M2*inv, P1); Y2 epilogue -> s5
  gemm_k<1, 1, 1, 0, 0><<<9 * BB, 256, 0, stream>>>(
      s3, s4, s5, s3, s4, trv, nullptr, 384, 384, 384,
      147456L, 147456L, 147456L, 0.f, 0.f, 3, 9);
  // T = 3I - NN(M2*inv, Y2) -> s6
  gemm_k<0, 1, 1, 0, 0><<<9 * BB, 256, 0, stream>>>(
      s3, s5, s6, nullptr, nullptr, trv, nullptr, 384, 384, 384,
      147456L, 147456L, 147456L, -1.f, 3.f, 3, 9);
  // V = triu(0.5 * NN(Y2, T)) / sqrt(tr+eps) -> s7 (packed)
  gemm_k<2, 1, 0, 0, 0><<<9 * BB, 256, 0, stream>>>(
      s5, s6, s7, nullptr, nullptr, trv, nullptr, 384, 384, 384,
      147456L, 147456L, 0L, 0.5f, 0.f, 3, 9);

  // part[kc] = V @ W2 chunk; then out = gelu(sum + b2)
  k_fc<<<dim3(4, FC_NCH), 256, 0, stream>>>(s7, W2, s8);
  k_reduce<<<(BB * DOUT) / 256, 256, 0, stream>>>(s8, b2, (float*)d_out);
}

// Round 19
// 276.897 us; speedup vs baseline: 2.9456x; 1.0367x over previous
//
#include <hip/hip_runtime.h>
#include <hip/hip_fp16.h>
#include <math.h>

#define DI 384
#define NSEQ 256
#define BB 64
#define DOUT 512
#define SID 73920
#define EPSV 1e-5f

typedef float f32x4 __attribute__((ext_vector_type(4)));
typedef short s16x8 __attribute__((ext_vector_type(8)));
typedef _Float16 f16x8 __attribute__((ext_vector_type(8)));

// ---------------- small kernels ----------------

// Fused degree + colw stage-1: one LDS-staged pass over each 32x256 graph
// tile computes invdeg (row sums) AND the colw partials (column sums of
// graph*invdeg). Saves k_deg's separate 67 MB read. ld=264: all LDS phases
// <=2-way bank aliasing (free).
__global__ __launch_bounds__(256) void k_colw1(const float* __restrict__ graph,
                                               float* __restrict__ ivd,
                                               float* __restrict__ part) {
  int b = blockIdx.x, nc = blockIdx.y;
  __shared__ float tile[32][264];
  __shared__ float ivl[32];
  const float* gb = graph + (size_t)b * NSEQ * NSEQ + (size_t)nc * 32 * NSEQ;
  int tid = threadIdx.x;
#pragma unroll 8
  for (int r = 0; r < 32; r++) tile[r][tid] = gb[(size_t)r * NSEQ + tid];
  __syncthreads();
  int r = tid >> 3, t8 = tid & 7;
  float s = 0.f;
#pragma unroll
  for (int i = 0; i < 32; i++) s += tile[r][t8 + i * 8];
  s += __shfl_xor(s, 1);
  s += __shfl_xor(s, 2);
  s += __shfl_xor(s, 4);
  if (t8 == 0) {
    float iv = 1.0f / (s + EPSV);
    ivl[r] = iv;
    ivd[(size_t)b * NSEQ + nc * 32 + r] = iv;
  }
  __syncthreads();
  float c = 0.f;
#pragma unroll
  for (int n = 0; n < 32; n++) c += tile[n][tid] * ivl[n];
  part[((size_t)nc * BB + b) * NSEQ + tid] = c;
}

__global__ __launch_bounds__(256) void k_colw2(const float* __restrict__ part,
                                               float* __restrict__ colw) {
  int idx = blockIdx.x * 256 + threadIdx.x;  // 64*256
  float s = 0.f;
#pragma unroll
  for (int nc = 0; nc < 8; nc++) s += part[(size_t)nc * BB * NSEQ + idx];
  colw[idx] = s;
}

// wmean 2-stage: wm[b][d] = sum_n colw[b][n]*tokens[b][n][d]
__global__ __launch_bounds__(384) void k_wmean1(const float* __restrict__ colw,
                                                const float* __restrict__ tokens,
                                                float* __restrict__ part) {
  int b = blockIdx.x, nc = blockIdx.y;
  int d = threadIdx.x;
  const float* t = tokens + (size_t)b * NSEQ * DI + (size_t)nc * 32 * DI + d;
  const float* cw = colw + b * NSEQ + nc * 32;
  float s = 0.f;
#pragma unroll
  for (int n = 0; n < 32; n++) s += cw[n] * t[(size_t)n * DI];
  part[((size_t)nc * BB + b) * DI + d] = s;
}

__global__ __launch_bounds__(256) void k_wmean2(const float* __restrict__ part,
                                                float* __restrict__ wm) {
  int idx = blockIdx.x * 256 + threadIdx.x;  // 64*384
  float s = 0.f;
#pragma unroll
  for (int nc = 0; nc < 8; nc++) s += part[(size_t)nc * BB * DI + idx];
  wm[idx] = s;
}

// ZT[b][d][n] = tokens[b][n][d] - wm[b][d]
__global__ __launch_bounds__(256) void k_zcT(const float* __restrict__ tokens,
                                             const float* __restrict__ wm,
                                             float* __restrict__ ZT) {
  int b = blockIdx.z;
  int d0 = blockIdx.x * 64, n0 = blockIdx.y * 64;
  __shared__ float ld[64][68];
  const float* Tb = tokens + (size_t)b * NSEQ * DI;
  const float* wmb = wm + (size_t)b * DI;
  float* Zb = ZT + (size_t)b * DI * NSEQ;
#pragma unroll
  for (int i = 0; i < 4; i++) {
    int sl = threadIdx.x + i * 256;
    int r = sl >> 4, q = sl & 15;
    float4 v = *(const float4*)&Tb[(size_t)(n0 + r) * DI + d0 + q * 4];
    float4 m = *(const float4*)&wmb[d0 + q * 4];
    v.x -= m.x; v.y -= m.y; v.z -= m.z; v.w -= m.w;
    *(float4*)&ld[r][q * 4] = v;
  }
  __syncthreads();
#pragma unroll
  for (int i = 0; i < 4; i++) {
    int sl = threadIdx.x + i * 256;
    int dl = sl >> 4, q = sl & 15;
    float4 v;
    v.x = ld[q * 4 + 0][dl];
    v.y = ld[q * 4 + 1][dl];
    v.z = ld[q * 4 + 2][dl];
    v.w = ld[q * 4 + 3][dl];
    *(float4*)&Zb[(size_t)(d0 + dl) * NSEQ + n0 + q * 4] = v;
  }
}

__global__ __launch_bounds__(256) void k_trace(const float* __restrict__ M2,
                                               float* __restrict__ tr) {
  int b = blockIdx.x;
  int t = threadIdx.x;
  float s = 0.f;
  for (int d = t; d < DI; d += 256)
    s += M2[(size_t)b * DI * DI + (size_t)d * DI + d];
  __shared__ float red[256];
  red[t] = s;
  __syncthreads();
  for (int st = 128; st > 0; st >>= 1) {
    if (t < st) red[t] += red[t + st];
    __syncthreads();
  }
  if (t == 0) tr[b] = red[0];
}

// ---------------- fp16 2-plane split helpers --------------------------------

__device__ __forceinline__ int swzB(int row, int s) {
  return (((row << 2) + s) ^ ((row >> 1) & 7)) << 3;  // in shorts
}

__device__ __forceinline__ unsigned splitpair_h(float a, float c, float& ra,
                                                float& rc) {
  __half2 h = __float22half2_rn(make_float2(a, c));
  unsigned u;
  __builtin_memcpy(&u, &h, 4);
  ra = a - __low2float(h);
  rc = c - __high2float(h);
  return u;
}

__device__ __forceinline__ unsigned packh2(float a, float c) {
  __half2 h = __float22half2_rn(make_float2(a, c));
  unsigned u;
  __builtin_memcpy(&u, &h, 4);
  return u;
}

__device__ __forceinline__ void split8v(float x0, float x1, float x2, float x3,
                                        float x4, float x5, float x6, float x7,
                                        short* dst, int ps) {
  unsigned h0, h1, h2, h3, m0, m1, m2, m3;
  float ra, rc;
  h0 = splitpair_h(x0, x1, ra, rc); m0 = packh2(ra, rc);
  h1 = splitpair_h(x2, x3, ra, rc); m1 = packh2(ra, rc);
  h2 = splitpair_h(x4, x5, ra, rc); m2 = packh2(ra, rc);
  h3 = splitpair_h(x6, x7, ra, rc); m3 = packh2(ra, rc);
  uint4 H, M;
  H.x = h0; H.y = h1; H.z = h2; H.w = h3;
  M.x = m0; M.y = m1; M.z = m2; M.w = m3;
  *(uint4*)(dst) = H;
  *(uint4*)(dst + ps) = M;
}

__device__ __forceinline__ void split8_h(f32x4 v0, f32x4 v1, short* dst, int ps) {
  split8v(v0[0], v0[1], v0[2], v0[3], v1[0], v1[1], v1[2], v1[3], dst, ps);
}

__device__ __forceinline__ f16x8 ldfrag(const short* p) {
  s16x8 t = *(const s16x8*)p;
  return __builtin_bit_cast(f16x8, t);
}

// ---------------- fp16-split MFMA GEMM --------------------------------------
// (256,3): occupancy optimum (r16 win; r17 (256,4) spills). MODE 2 enumerates
// only upper-triangular tiles (6 of 9): below-diagonal tiles write nothing.
template <int MODE, int BSTAGE, int ASCL, int BSCL, int BRSCL>
__global__ __launch_bounds__(256, 3) void gemm_k(
    const float* __restrict__ pA, const float* __restrict__ pB,
    float* __restrict__ pC, const float* __restrict__ pMn,
    const float* __restrict__ pP1, const float* __restrict__ trv,
    const float* __restrict__ pRScl, int K, int lda, int ldb, long sA, long sB,
    long sC, float alpha, float diagAdd, int ntn, int ntile) {
  __shared__ short As[2 * 128 * 32];
  __shared__ short Bs[2 * 128 * 32];
  int flat = blockIdx.x;
  int q = flat >> 3;
  int b = (flat & 7) + (q / ntile) * 8;
  int tk = q % ntile;
  int m0, n0;
  if (MODE == 2) {
    int mm, nn;
    if (tk < 3) { mm = 0; nn = tk; }
    else if (tk < 5) { mm = 1; nn = tk - 2; }
    else { mm = 2; nn = 2; }
    m0 = mm * 128; n0 = nn * 128;
  } else {
    m0 = (tk / ntn) * 128;
    n0 = (tk % ntn) * 128;
  }
  int tid = threadIdx.x;
  int lane = tid & 63, wid = tid >> 6;
  int wm = wid >> 1, wn = wid & 1;
  int lr = lane & 15, lg = lane >> 4;
  float inv = 0.f;
  if (ASCL || BSCL || MODE == 1) inv = 1.0f / (trv[b] + EPSV);

  int rowA = tid >> 1, subA = tid & 1;
  int oA0 = swzB(rowA, 2 * subA), oA1 = swzB(rowA, 2 * subA + 1);
  const float* Aptr = pA + (size_t)b * sA + (size_t)(m0 + rowA) * lda + subA * 16;

  int rowB = tid >> 1;
  const float* Bptr;
  int oB0, oB1;
  float rscl = 1.f;
  if (BSTAGE == 0) {
    int subB = tid & 1;
    oB0 = swzB(rowB, 2 * subB);
    oB1 = swzB(rowB, 2 * subB + 1);
    Bptr = pB + (size_t)b * sB + (size_t)(n0 + rowB) * ldb + subB * 16;
    if (BRSCL) rscl = pRScl[(size_t)b * NSEQ + n0 + rowB];
  } else {
    int nB = (tid & 63) * 2, kk8 = (tid >> 6) * 8;
    oB0 = swzB(nB, kk8 >> 3);
    oB1 = swzB(nB + 1, kk8 >> 3);
    Bptr = pB + (size_t)b * sB + (size_t)kk8 * ldb + n0 + nB;
  }

  f32x4 acc[4][4] = {};
  f32x4 a0, a1, a2, a3;
  f32x4 t0, t1, t2, t3;
  float2 q0, q1, q2, q3, q4, q5, q6, q7;

#define LOAD_A(OFF)                      \
  a0 = *(const f32x4*)(Aptr + (OFF));    \
  a1 = *(const f32x4*)(Aptr + (OFF) + 4);\
  a2 = *(const f32x4*)(Aptr + (OFF) + 8);\
  a3 = *(const f32x4*)(Aptr + (OFF) + 12);

#define STORE_A()                                            \
  {                                                          \
    if (ASCL) { a0 *= inv; a1 *= inv; a2 *= inv; a3 *= inv; }\
    split8_h(a0, a1, As + oA0, 4096);                        \
    split8_h(a2, a3, As + oA1, 4096);                        \
  }

#define LOAD_B(OFF)                                              \
  if (BSTAGE == 0) {                                             \
    t0 = *(const f32x4*)(Bptr + (OFF));                          \
    t1 = *(const f32x4*)(Bptr + (OFF) + 4);                      \
    t2 = *(const f32x4*)(Bptr + (OFF) + 8);                      \
    t3 = *(const f32x4*)(Bptr + (OFF) + 12);                     \
  } else {                                                       \
    const float* bp = Bptr + (size_t)(OFF) * ldb;                \
    q0 = *(const float2*)(bp);                                   \
    q1 = *(const float2*)(bp + ldb);                             \
    q2 = *(const float2*)(bp + 2 * ldb);                         \
    q3 = *(const float2*)(bp + 3 * ldb);                         \
    q4 = *(const float2*)(bp + 4 * ldb);                         \
    q5 = *(const float2*)(bp + 5 * ldb);                         \
    q6 = *(const float2*)(bp + 6 * ldb);                         \
    q7 = *(const float2*)(bp + 7 * ldb);                         \
  }

#define STORE_B()                                                              \
  if (BSTAGE == 0) {                                                           \
    if (BSCL) { t0 *= inv; t1 *= inv; t2 *= inv; t3 *= inv; }                  \
    if (BRSCL) { t0 *= rscl; t1 *= rscl; t2 *= rscl; t3 *= rscl; }             \
    split8_h(t0, t1, Bs + oB0, 4096);                                          \
    split8_h(t2, t3, Bs + oB1, 4096);                                          \
  } else {                                                                     \
    if (BSCL) {                                                                \
      q0.x *= inv; q0.y *= inv; q1.x *= inv; q1.y *= inv;                      \
      q2.x *= inv; q2.y *= inv; q3.x *= inv; q3.y *= inv;                      \
      q4.x *= inv; q4.y *= inv; q5.x *= inv; q5.y *= inv;                      \
      q6.x *= inv; q6.y *= inv; q7.x *= inv; q7.y *= inv;                      \
    }                                                                          \
    split8v(q0.x, q1.x, q2.x, q3.x, q4.x, q5.x, q6.x, q7.x, Bs + oB0, 4096);   \
    split8v(q0.y, q1.y, q2.y, q3.y, q4.y, q5.y, q6.y, q7.y, Bs + oB1, 4096);   \
  }

  LOAD_A(0)
  LOAD_B(0)
  STORE_A()
  STORE_B()
  __syncthreads();

  for (int k0 = 0; k0 < K; k0 += 32) {
    bool more = (k0 + 32) < K;
    if (more) {
      LOAD_A(k0 + 32)
      LOAD_B(k0 + 32)
    }
    f16x8 ah[4], bh[4];
#pragma unroll
    for (int mi = 0; mi < 4; mi++)
      ah[mi] = ldfrag(As + swzB(wm * 64 + mi * 16 + lr, lg));
#pragma unroll
    for (int ni = 0; ni < 4; ni++)
      bh[ni] = ldfrag(Bs + swzB(wn * 64 + ni * 16 + lr, lg));
#pragma unroll
    for (int ni = 0; ni < 4; ni++)
#pragma unroll
      for (int mi = 0; mi < 4; mi++)
        acc[mi][ni] = __builtin_amdgcn_mfma_f32_16x16x32_f16(
            ah[mi], bh[ni], acc[mi][ni], 0, 0, 0);
    {
      f16x8 bm[4];
#pragma unroll
      for (int ni = 0; ni < 4; ni++)
        bm[ni] = ldfrag(Bs + 4096 + swzB(wn * 64 + ni * 16 + lr, lg));
#pragma unroll
      for (int ni = 0; ni < 4; ni++)
#pragma unroll
        for (int mi = 0; mi < 4; mi++)
          acc[mi][ni] = __builtin_amdgcn_mfma_f32_16x16x32_f16(
              ah[mi], bm[ni], acc[mi][ni], 0, 0, 0);
    }
    {
      f16x8 am[4];
#pragma unroll
      for (int mi = 0; mi < 4; mi++)
        am[mi] = ldfrag(As + 4096 + swzB(wm * 64 + mi * 16 + lr, lg));
#pragma unroll
      for (int ni = 0; ni < 4; ni++)
#pragma unroll
        for (int mi = 0; mi < 4; mi++)
          acc[mi][ni] = __builtin_amdgcn_mfma_f32_16x16x32_f16(
              am[mi], bh[ni], acc[mi][ni], 0, 0, 0);
    }
    __syncthreads();
    if (more) {
      STORE_A()
      STORE_B()
    }
    __syncthreads();
  }

  const size_t cb = (size_t)b * sC;
  float invs = 0.f;
  if (MODE == 2) invs = 1.0f / sqrtf(trv[b] + EPSV);
#pragma unroll
  for (int mi = 0; mi < 4; mi++)
#pragma unroll
    for (int ni = 0; ni < 4; ni++)
#pragma unroll
      for (int j = 0; j < 4; j++) {
        int rowc = m0 + wm * 64 + mi * 16 + lg * 4 + j;
        int colc = n0 + wn * 64 + ni * 16 + lr;
        float v = acc[mi][ni][j];
        if (MODE == 0) {
          float o = alpha * v;
          if (rowc == colc) o += diagAdd;
          pC[cb + (size_t)rowc * 384 + colc] = o;
        } else if (MODE == 1) {
          size_t ix = cb + (size_t)rowc * 384 + colc;
          float mn = pMn[ix] * inv;
          float p1 = pP1[ix];
          float y2 = -1.875f * mn + 0.75f * p1 - 0.125f * v;
          if (rowc == colc) y2 += 2.25f;
          pC[ix] = y2;
        } else {
          if (colc >= rowc) {
            long idx = (long)b * SID + (long)rowc * 384 -
                       (long)rowc * (rowc - 1) / 2 + (colc - rowc);
            pC[idx] = alpha * v * invs;
          }
        }
      }
#undef LOAD_A
#undef STORE_A
#undef LOAD_B
#undef STORE_B
}

// ---------------- FC: part[kc] = V @ W2 (320-k chunk, 924 blocks) -----------
#define FC_NCH 231

__global__ __launch_bounds__(256, 3) void k_fc(const float* __restrict__ V,
                                               const float* __restrict__ W2,
                                               float* __restrict__ part) {
  __shared__ short As[2 * 64 * 32];
  __shared__ short Bs[2 * 128 * 32];
  int n0 = blockIdx.x * 128;
  int kc = blockIdx.y;
  int tid = threadIdx.x;
  int lane = tid & 63, wid = tid >> 6;
  int wm = wid >> 1, wn = wid & 1;
  int lr = lane & 15, lg = lane >> 4;
  int rowA = tid >> 2, subA = tid & 3;
  int oA = swzB(rowA, subA);
  int nB = tid >> 1, kh = tid & 1;
  int oB0 = swzB(nB, 2 * kh), oB1 = swzB(nB, 2 * kh + 1);
  const float* Aptr = V + (size_t)rowA * SID + kc * 320 + subA * 8;
  const float* Bptr = W2 + (size_t)(kc * 320 + kh * 16) * DOUT + n0 + nB;
  f32x4 acc[2][4] = {};
  f32x4 a0, a1, w0, w1, w2, w3;

#define FC_LOADB(off)                                                       \
  {                                                                         \
    const float* bp = Bptr + (size_t)(off) * DOUT;                          \
    w0[0] = bp[0 * DOUT];  w0[1] = bp[1 * DOUT];                            \
    w0[2] = bp[2 * DOUT];  w0[3] = bp[3 * DOUT];                            \
    w1[0] = bp[4 * DOUT];  w1[1] = bp[5 * DOUT];                            \
    w1[2] = bp[6 * DOUT];  w1[3] = bp[7 * DOUT];                            \
    w2[0] = bp[8 * DOUT];  w2[1] = bp[9 * DOUT];                            \
    w2[2] = bp[10 * DOUT]; w2[3] = bp[11 * DOUT];                           \
    w3[0] = bp[12 * DOUT]; w3[1] = bp[13 * DOUT];                           \
    w3[2] = bp[14 * DOUT]; w3[3] = bp[15 * DOUT];                           \
  }

  a0 = *(const f32x4*)(Aptr + 0);
  a1 = *(const f32x4*)(Aptr + 4);
  FC_LOADB(0);
  split8_h(a0, a1, As + oA, 2048);
  split8_h(w0, w1, Bs + oB0, 4096);
  split8_h(w2, w3, Bs + oB1, 4096);
  __syncthreads();

  for (int st = 0; st < 10; st++) {
    bool more = st < 9;
    if (more) {
      a0 = *(const f32x4*)(Aptr + (st + 1) * 32);
      a1 = *(const f32x4*)(Aptr + (st + 1) * 32 + 4);
      FC_LOADB((st + 1) * 32);
    }
#pragma unroll
    for (int ib = 0; ib < 2; ib++) {
      f16x8 bfr[4];
#pragma unroll
      for (int ni = 0; ni < 4; ni++)
        bfr[ni] = ldfrag(Bs + ib * 4096 + swzB(wn * 64 + ni * 16 + lr, lg));
#pragma unroll
      for (int ia = 0; ia < 2; ia++) {
        if (ia + ib > 1) continue;
        f16x8 afr[2];
#pragma unroll
        for (int mi = 0; mi < 2; mi++)
          afr[mi] = ldfrag(As + ia * 2048 + swzB(wm * 32 + mi * 16 + lr, lg));
#pragma unroll
        for (int ni = 0; ni < 4; ni++)
#pragma unroll
          for (int mi = 0; mi < 2; mi++)
            acc[mi][ni] = __builtin_amdgcn_mfma_f32_16x16x32_f16(
                afr[mi], bfr[ni], acc[mi][ni], 0, 0, 0);
      }
    }
    __syncthreads();
    if (more) {
      split8_h(a0, a1, As + oA, 2048);
      split8_h(w0, w1, Bs + oB0, 4096);
      split8_h(w2, w3, Bs + oB1, 4096);
    }
    __syncthreads();
  }

  float* p = part + (size_t)kc * (BB * DOUT) + n0;
#pragma unroll
  for (int mi = 0; mi < 2; mi++)
#pragma unroll
    for (int ni = 0; ni < 4; ni++)
#pragma unroll
      for (int j = 0; j < 4; j++)
        p[(size_t)(wm * 32 + mi * 16 + lg * 4 + j) * DOUT + wn * 64 + ni * 16 + lr] =
            acc[mi][ni][j];
}

__global__ __launch_bounds__(256) void k_reduce(const float* __restrict__ part,
                                                const float* __restrict__ b2,
                                                float* __restrict__ out) {
  int idx = blockIdx.x * 256 + threadIdx.x;
  int c = idx & (DOUT - 1);
  float s = 0.f;
  for (int kc = 0; kc < FC_NCH; kc++) s += part[(size_t)kc * BB * DOUT + idx];
  float x = s + b2[c];
  out[idx] = 0.5f * x * (1.0f + erff(x * 0.70710678118654752f));
}

// ---------------- launch ----------------

extern "C" void kernel_launch(void* const* d_in, const int* in_sizes, int n_in,
                              void* d_out, int out_size, void* d_ws, size_t ws_size,
                              hipStream_t stream) {
  (void)in_sizes; (void)n_in; (void)out_size; (void)ws_size;
  const float* tokens = (const float*)d_in[0];
  const float* graph = (const float*)d_in[1];
  const float* W2 = (const float*)d_in[2];
  const float* b2 = (const float*)d_in[3];

  float* ws = (float*)d_ws;
  const long NM = 9437184L;
  float* s1 = ws + NM;        // ZT
  float* s2 = ws + 2 * NM;    // WZT (ld 384)
  float* s3 = ws + 3 * NM;    // M2 (raw, unscaled)
  float* s4 = ws + 4 * NM;    // P1
  float* s5 = ws + 5 * NM;    // Y2
  float* s6 = ws + 6 * NM;    // T
  float* s7 = ws + 7 * NM;    // V (packed triu)
  float* s8 = ws + 8 * NM;    // part
  float* colw = ws + 9 * NM;
  float* wmv = colw + BB * NSEQ;
  float* trv = wmv + BB * DI;
  float* colwp = trv + BB;              // 8*64*256 partials
  float* wmp = colwp + 8 * BB * NSEQ;   // 8*64*384 partials
  float* ivd = wmp + 8 * BB * DI;       // 64*256 inv-degrees

  k_colw1<<<dim3(BB, 8), 256, 0, stream>>>(graph, ivd, colwp);
  k_colw2<<<BB, 256, 0, stream>>>(colwp, colw);
  k_wmean1<<<dim3(BB, 8), 384, 0, stream>>>(colw, tokens, wmp);
  k_wmean2<<<(BB * DI) / 256, 256, 0, stream>>>(wmp, wmv);
  k_zcT<<<dim3(6, 4, BB), 256, 0, stream>>>(tokens, wmv, s1);

  // WZT[e][n] = sum_k ZT[e][k] * (graph[n][k]*ivd[n])  (NT + BRSCL) -> s2
  gemm_k<0, 0, 0, 0, 1><<<6 * BB, 256, 0, stream>>>(
      s1, graph, s2, nullptr, nullptr, nullptr, ivd, 256, 256, 256,
      98304L, 65536L, 147456L, 1.f, 0.f, 2, 6);
  // M2[d][e] = sum_n ZT[d][n] WZT[e][n]  (NT; M=N=384,K=256) -> s3
  gemm_k<0, 0, 0, 0, 0><<<9 * BB, 256, 0, stream>>>(
      s1, s2, s3, nullptr, nullptr, nullptr, nullptr, 256, 256, 384,
      98304L, 147456L, 147456L, 1.f, 0.f, 3, 9);

  k_trace<<<BB, 256, 0, stream>>>(s3, trv);

  // P1 = NN(M2*inv, M2*inv) -> s4
  gemm_k<0, 1, 1, 1, 0><<<9 * BB, 256, 0, stream>>>(
      s3, s3, s4, nullptr, nullptr, trv, nullptr, 384, 384, 384,
      147456L, 147456L, 147456L, 1.f, 0.f, 3, 9);
  // H = NN(M2*inv, P1); Y2 epilogue -> s5
  gemm_k<1, 1, 1, 0, 0><<<9 * BB, 256, 0, stream>>>(
      s3, s4, s5, s3, s4, trv, nullptr, 384, 384, 384,
      147456L, 147456L, 147456L, 0.f, 0.f, 3, 9);
  // T = 3I - NN(M2*inv, Y2) -> s6
  gemm_k<0, 1, 1, 0, 0><<<9 * BB, 256, 0, stream>>>(
      s3, s5, s6, nullptr, nullptr, trv, nullptr, 384, 384, 384,
      147456L, 147456L, 147456L, -1.f, 3.f, 3, 9);
  // V = triu(0.5 * NN(Y2, T)) / sqrt(tr+eps) -> s7 (packed; upper tiles only)
  gemm_k<2, 1, 0, 0, 0><<<6 * BB, 256, 0, stream>>>(
      s5, s6, s7, nullptr, nullptr, trv, nullptr, 384, 384, 384,
      147456L, 147456L, 0L, 0.5f, 0.f, 3, 6);

  // part[kc] = V @ W2 chunk; then out = gelu(sum + b2)
  k_fc<<<dim3(4, FC_NCH), 256, 0, stream>>>(s7, W2, s8);
  k_reduce<<<(BB * DOUT) / 256, 256, 0, stream>>>(s8, b2, (float*)d_out);
}

// Round 20
// 273.289 us; speedup vs baseline: 2.9845x; 1.0132x over previous
//
#include <hip/hip_runtime.h>
#include <hip/hip_fp16.h>
#include <math.h>

#define DI 384
#define NSEQ 256
#define BB 64
#define DOUT 512
#define SID 73920
#define EPSV 1e-5f

typedef float f32x4 __attribute__((ext_vector_type(4)));
typedef short s16x8 __attribute__((ext_vector_type(8)));
typedef _Float16 f16x8 __attribute__((ext_vector_type(8)));

// ---------------- small kernels ----------------

// Fused degree + colw stage-1 (r19): one LDS pass over each 32x256 graph tile
// yields invdeg and the colw partials.
__global__ __launch_bounds__(256) void k_colw1(const float* __restrict__ graph,
                                               float* __restrict__ ivd,
                                               float* __restrict__ part) {
  int b = blockIdx.x, nc = blockIdx.y;
  __shared__ float tile[32][264];
  __shared__ float ivl[32];
  const float* gb = graph + (size_t)b * NSEQ * NSEQ + (size_t)nc * 32 * NSEQ;
  int tid = threadIdx.x;
#pragma unroll 8
  for (int r = 0; r < 32; r++) tile[r][tid] = gb[(size_t)r * NSEQ + tid];
  __syncthreads();
  int r = tid >> 3, t8 = tid & 7;
  float s = 0.f;
#pragma unroll
  for (int i = 0; i < 32; i++) s += tile[r][t8 + i * 8];
  s += __shfl_xor(s, 1);
  s += __shfl_xor(s, 2);
  s += __shfl_xor(s, 4);
  if (t8 == 0) {
    float iv = 1.0f / (s + EPSV);
    ivl[r] = iv;
    ivd[(size_t)b * NSEQ + nc * 32 + r] = iv;
  }
  __syncthreads();
  float c = 0.f;
#pragma unroll
  for (int n = 0; n < 32; n++) c += tile[n][tid] * ivl[n];
  part[((size_t)nc * BB + b) * NSEQ + tid] = c;
}

// wmean stage-1 with colw-partial reduction fused in (r20): colw[b][n] is the
// nc-ascending sum of 8 partials -- identical order to the old k_colw2, so the
// result is bit-identical.
__global__ __launch_bounds__(384) void k_wmean1(const float* __restrict__ colwp,
                                                const float* __restrict__ tokens,
                                                float* __restrict__ part) {
  int b = blockIdx.x, nc = blockIdx.y;
  int d = threadIdx.x;
  __shared__ float cw[32];
  if (d < 32) {
    int n = nc * 32 + d;
    float s = 0.f;
#pragma unroll
    for (int p = 0; p < 8; p++)
      s += colwp[(size_t)p * BB * NSEQ + (size_t)b * NSEQ + n];
    cw[d] = s;
  }
  __syncthreads();
  const float* t = tokens + (size_t)b * NSEQ * DI + (size_t)nc * 32 * DI + d;
  float s = 0.f;
#pragma unroll
  for (int n = 0; n < 32; n++) s += cw[n] * t[(size_t)n * DI];
  part[((size_t)nc * BB + b) * DI + d] = s;
}

// ZT[b][d][n] = tokens[b][n][d] - wm[b][d], with the wm-partial reduction
// fused in (r20): nc-ascending sum identical to the old k_wmean2.
__global__ __launch_bounds__(256) void k_zcT(const float* __restrict__ tokens,
                                             const float* __restrict__ wmp,
                                             float* __restrict__ ZT) {
  int b = blockIdx.z;
  int d0 = blockIdx.x * 64, n0 = blockIdx.y * 64;
  __shared__ float ld[64][68];
  __shared__ float wml[64];
  int tid = threadIdx.x;
  if (tid < 64) {
    float s = 0.f;
#pragma unroll
    for (int p = 0; p < 8; p++)
      s += wmp[(size_t)p * BB * DI + (size_t)b * DI + d0 + tid];
    wml[tid] = s;
  }
  __syncthreads();
  const float* Tb = tokens + (size_t)b * NSEQ * DI;
  float* Zb = ZT + (size_t)b * DI * NSEQ;
#pragma unroll
  for (int i = 0; i < 4; i++) {
    int sl = tid + i * 256;
    int r = sl >> 4, q = sl & 15;
    float4 v = *(const float4*)&Tb[(size_t)(n0 + r) * DI + d0 + q * 4];
    v.x -= wml[q * 4 + 0];
    v.y -= wml[q * 4 + 1];
    v.z -= wml[q * 4 + 2];
    v.w -= wml[q * 4 + 3];
    *(float4*)&ld[r][q * 4] = v;
  }
  __syncthreads();
#pragma unroll
  for (int i = 0; i < 4; i++) {
    int sl = tid + i * 256;
    int dl = sl >> 4, q = sl & 15;
    float4 v;
    v.x = ld[q * 4 + 0][dl];
    v.y = ld[q * 4 + 1][dl];
    v.z = ld[q * 4 + 2][dl];
    v.w = ld[q * 4 + 3][dl];
    *(float4*)&Zb[(size_t)(d0 + dl) * NSEQ + n0 + q * 4] = v;
  }
}

__global__ __launch_bounds__(256) void k_trace(const float* __restrict__ M2,
                                               float* __restrict__ tr) {
  int b = blockIdx.x;
  int t = threadIdx.x;
  float s = 0.f;
  for (int d = t; d < DI; d += 256)
    s += M2[(size_t)b * DI * DI + (size_t)d * DI + d];
  __shared__ float red[256];
  red[t] = s;
  __syncthreads();
  for (int st = 128; st > 0; st >>= 1) {
    if (t < st) red[t] += red[t + st];
    __syncthreads();
  }
  if (t == 0) tr[b] = red[0];
}

// ---------------- fp16 2-plane split helpers --------------------------------

__device__ __forceinline__ int swzB(int row, int s) {
  return (((row << 2) + s) ^ ((row >> 1) & 7)) << 3;  // in shorts
}

__device__ __forceinline__ unsigned splitpair_h(float a, float c, float& ra,
                                                float& rc) {
  __half2 h = __float22half2_rn(make_float2(a, c));
  unsigned u;
  __builtin_memcpy(&u, &h, 4);
  ra = a - __low2float(h);
  rc = c - __high2float(h);
  return u;
}

__device__ __forceinline__ unsigned packh2(float a, float c) {
  __half2 h = __float22half2_rn(make_float2(a, c));
  unsigned u;
  __builtin_memcpy(&u, &h, 4);
  return u;
}

__device__ __forceinline__ void split8v(float x0, float x1, float x2, float x3,
                                        float x4, float x5, float x6, float x7,
                                        short* dst, int ps) {
  unsigned h0, h1, h2, h3, m0, m1, m2, m3;
  float ra, rc;
  h0 = splitpair_h(x0, x1, ra, rc); m0 = packh2(ra, rc);
  h1 = splitpair_h(x2, x3, ra, rc); m1 = packh2(ra, rc);
  h2 = splitpair_h(x4, x5, ra, rc); m2 = packh2(ra, rc);
  h3 = splitpair_h(x6, x7, ra, rc); m3 = packh2(ra, rc);
  uint4 H, M;
  H.x = h0; H.y = h1; H.z = h2; H.w = h3;
  M.x = m0; M.y = m1; M.z = m2; M.w = m3;
  *(uint4*)(dst) = H;
  *(uint4*)(dst + ps) = M;
}

__device__ __forceinline__ void split8_h(f32x4 v0, f32x4 v1, short* dst, int ps) {
  split8v(v0[0], v0[1], v0[2], v0[3], v1[0], v1[1], v1[2], v1[3], dst, ps);
}

__device__ __forceinline__ f16x8 ldfrag(const short* p) {
  s16x8 t = *(const s16x8*)p;
  return __builtin_bit_cast(f16x8, t);
}

// ---------------- fp16-split MFMA GEMM --------------------------------------
// (256,3): occupancy optimum (r16 win; r17 (256,4) spills). MODE 2 enumerates
// only upper-triangular tiles (6 of 9).
template <int MODE, int BSTAGE, int ASCL, int BSCL, int BRSCL>
__global__ __launch_bounds__(256, 3) void gemm_k(
    const float* __restrict__ pA, const float* __restrict__ pB,
    float* __restrict__ pC, const float* __restrict__ pMn,
    const float* __restrict__ pP1, const float* __restrict__ trv,
    const float* __restrict__ pRScl, int K, int lda, int ldb, long sA, long sB,
    long sC, float alpha, float diagAdd, int ntn, int ntile) {
  __shared__ short As[2 * 128 * 32];
  __shared__ short Bs[2 * 128 * 32];
  int flat = blockIdx.x;
  int q = flat >> 3;
  int b = (flat & 7) + (q / ntile) * 8;
  int tk = q % ntile;
  int m0, n0;
  if (MODE == 2) {
    int mm, nn;
    if (tk < 3) { mm = 0; nn = tk; }
    else if (tk < 5) { mm = 1; nn = tk - 2; }
    else { mm = 2; nn = 2; }
    m0 = mm * 128; n0 = nn * 128;
  } else {
    m0 = (tk / ntn) * 128;
    n0 = (tk % ntn) * 128;
  }
  int tid = threadIdx.x;
  int lane = tid & 63, wid = tid >> 6;
  int wm = wid >> 1, wn = wid & 1;
  int lr = lane & 15, lg = lane >> 4;
  float inv = 0.f;
  if (ASCL || BSCL || MODE == 1) inv = 1.0f / (trv[b] + EPSV);

  int rowA = tid >> 1, subA = tid & 1;
  int oA0 = swzB(rowA, 2 * subA), oA1 = swzB(rowA, 2 * subA + 1);
  const float* Aptr = pA + (size_t)b * sA + (size_t)(m0 + rowA) * lda + subA * 16;

  int rowB = tid >> 1;
  const float* Bptr;
  int oB0, oB1;
  float rscl = 1.f;
  if (BSTAGE == 0) {
    int subB = tid & 1;
    oB0 = swzB(rowB, 2 * subB);
    oB1 = swzB(rowB, 2 * subB + 1);
    Bptr = pB + (size_t)b * sB + (size_t)(n0 + rowB) * ldb + subB * 16;
    if (BRSCL) rscl = pRScl[(size_t)b * NSEQ + n0 + rowB];
  } else {
    int nB = (tid & 63) * 2, kk8 = (tid >> 6) * 8;
    oB0 = swzB(nB, kk8 >> 3);
    oB1 = swzB(nB + 1, kk8 >> 3);
    Bptr = pB + (size_t)b * sB + (size_t)kk8 * ldb + n0 + nB;
  }

  f32x4 acc[4][4] = {};
  f32x4 a0, a1, a2, a3;
  f32x4 t0, t1, t2, t3;
  float2 q0, q1, q2, q3, q4, q5, q6, q7;

#define LOAD_A(OFF)                      \
  a0 = *(const f32x4*)(Aptr + (OFF));    \
  a1 = *(const f32x4*)(Aptr + (OFF) + 4);\
  a2 = *(const f32x4*)(Aptr + (OFF) + 8);\
  a3 = *(const f32x4*)(Aptr + (OFF) + 12);

#define STORE_A()                                            \
  {                                                          \
    if (ASCL) { a0 *= inv; a1 *= inv; a2 *= inv; a3 *= inv; }\
    split8_h(a0, a1, As + oA0, 4096);                        \
    split8_h(a2, a3, As + oA1, 4096);                        \
  }

#define LOAD_B(OFF)                                              \
  if (BSTAGE == 0) {                                             \
    t0 = *(const f32x4*)(Bptr + (OFF));                          \
    t1 = *(const f32x4*)(Bptr + (OFF) + 4);                      \
    t2 = *(const f32x4*)(Bptr + (OFF) + 8);                      \
    t3 = *(const f32x4*)(Bptr + (OFF) + 12);                     \
  } else {                                                       \
    const float* bp = Bptr + (size_t)(OFF) * ldb;                \
    q0 = *(const float2*)(bp);                                   \
    q1 = *(const float2*)(bp + ldb);                             \
    q2 = *(const float2*)(bp + 2 * ldb);                         \
    q3 = *(const float2*)(bp + 3 * ldb);                         \
    q4 = *(const float2*)(bp + 4 * ldb);                         \
    q5 = *(const float2*)(bp + 5 * ldb);                         \
    q6 = *(const float2*)(bp + 6 * ldb);                         \
    q7 = *(const float2*)(bp + 7 * ldb);                         \
  }

#define STORE_B()                                                              \
  if (BSTAGE == 0) {                                                           \
    if (BSCL) { t0 *= inv; t1 *= inv; t2 *= inv; t3 *= inv; }                  \
    if (BRSCL) { t0 *= rscl; t1 *= rscl; t2 *= rscl; t3 *= rscl; }             \
    split8_h(t0, t1, Bs + oB0, 4096);                                          \
    split8_h(t2, t3, Bs + oB1, 4096);                                          \
  } else {                                                                     \
    if (BSCL) {                                                                \
      q0.x *= inv; q0.y *= inv; q1.x *= inv; q1.y *= inv;                      \
      q2.x *= inv; q2.y *= inv; q3.x *= inv; q3.y *= inv;                      \
      q4.x *= inv; q4.y *= inv; q5.x *= inv; q5.y *= inv;                      \
      q6.x *= inv; q6.y *= inv; q7.x *= inv; q7.y *= inv;                      \
    }                                                                          \
    split8v(q0.x, q1.x, q2.x, q3.x, q4.x, q5.x, q6.x, q7.x, Bs + oB0, 4096);   \
    split8v(q0.y, q1.y, q2.y, q3.y, q4.y, q5.y, q6.y, q7.y, Bs + oB1, 4096);   \
  }

  LOAD_A(0)
  LOAD_B(0)
  STORE_A()
  STORE_B()
  __syncthreads();

  for (int k0 = 0; k0 < K; k0 += 32) {
    bool more = (k0 + 32) < K;
    if (more) {
      LOAD_A(k0 + 32)
      LOAD_B(k0 + 32)
    }
    f16x8 ah[4], bh[4];
#pragma unroll
    for (int mi = 0; mi < 4; mi++)
      ah[mi] = ldfrag(As + swzB(wm * 64 + mi * 16 + lr, lg));
#pragma unroll
    for (int ni = 0; ni < 4; ni++)
      bh[ni] = ldfrag(Bs + swzB(wn * 64 + ni * 16 + lr, lg));
#pragma unroll
    for (int ni = 0; ni < 4; ni++)
#pragma unroll
      for (int mi = 0; mi < 4; mi++)
        acc[mi][ni] = __builtin_amdgcn_mfma_f32_16x16x32_f16(
            ah[mi], bh[ni], acc[mi][ni], 0, 0, 0);
    {
      f16x8 bm[4];
#pragma unroll
      for (int ni = 0; ni < 4; ni++)
        bm[ni] = ldfrag(Bs + 4096 + swzB(wn * 64 + ni * 16 + lr, lg));
#pragma unroll
      for (int ni = 0; ni < 4; ni++)
#pragma unroll
        for (int mi = 0; mi < 4; mi++)
          acc[mi][ni] = __builtin_amdgcn_mfma_f32_16x16x32_f16(
              ah[mi], bm[ni], acc[mi][ni], 0, 0, 0);
    }
    {
      f16x8 am[4];
#pragma unroll
      for (int mi = 0; mi < 4; mi++)
        am[mi] = ldfrag(As + 4096 + swzB(wm * 64 + mi * 16 + lr, lg));
#pragma unroll
      for (int ni = 0; ni < 4; ni++)
#pragma unroll
        for (int mi = 0; mi < 4; mi++)
          acc[mi][ni] = __builtin_amdgcn_mfma_f32_16x16x32_f16(
              am[mi], bh[ni], acc[mi][ni], 0, 0, 0);
    }
    __syncthreads();
    if (more) {
      STORE_A()
      STORE_B()
    }
    __syncthreads();
  }

  const size_t cb = (size_t)b * sC;
  float invs = 0.f;
  if (MODE == 2) invs = 1.0f / sqrtf(trv[b] + EPSV);
#pragma unroll
  for (int mi = 0; mi < 4; mi++)
#pragma unroll
    for (int ni = 0; ni < 4; ni++)
#pragma unroll
      for (int j = 0; j < 4; j++) {
        int rowc = m0 + wm * 64 + mi * 16 + lg * 4 + j;
        int colc = n0 + wn * 64 + ni * 16 + lr;
        float v = acc[mi][ni][j];
        if (MODE == 0) {
          float o = alpha * v;
          if (rowc == colc) o += diagAdd;
          pC[cb + (size_t)rowc * 384 + colc] = o;
        } else if (MODE == 1) {
          size_t ix = cb + (size_t)rowc * 384 + colc;
          float mn = pMn[ix] * inv;
          float p1 = pP1[ix];
          float y2 = -1.875f * mn + 0.75f * p1 - 0.125f * v;
          if (rowc == colc) y2 += 2.25f;
          pC[ix] = y2;
        } else {
          if (colc >= rowc) {
            long idx = (long)b * SID + (long)rowc * 384 -
                       (long)rowc * (rowc - 1) / 2 + (colc - rowc);
            pC[idx] = alpha * v * invs;
          }
        }
      }
#undef LOAD_A
#undef STORE_A
#undef LOAD_B
#undef STORE_B
}

// ---------------- FC: part[kc] = V @ W2 (320-k chunk, 924 blocks) -----------
#define FC_NCH 231

__global__ __launch_bounds__(256, 3) void k_fc(const float* __restrict__ V,
                                               const float* __restrict__ W2,
                                               float* __restrict__ part) {
  __shared__ short As[2 * 64 * 32];
  __shared__ short Bs[2 * 128 * 32];
  int n0 = blockIdx.x * 128;
  int kc = blockIdx.y;
  int tid = threadIdx.x;
  int lane = tid & 63, wid = tid >> 6;
  int wm = wid >> 1, wn = wid & 1;
  int lr = lane & 15, lg = lane >> 4;
  int rowA = tid >> 2, subA = tid & 3;
  int oA = swzB(rowA, subA);
  int nB = tid >> 1, kh = tid & 1;
  int oB0 = swzB(nB, 2 * kh), oB1 = swzB(nB, 2 * kh + 1);
  const float* Aptr = V + (size_t)rowA * SID + kc * 320 + subA * 8;
  const float* Bptr = W2 + (size_t)(kc * 320 + kh * 16) * DOUT + n0 + nB;
  f32x4 acc[2][4] = {};
  f32x4 a0, a1, w0, w1, w2, w3;

#define FC_LOADB(off)                                                       \
  {                                                                         \
    const float* bp = Bptr + (size_t)(off) * DOUT;                          \
    w0[0] = bp[0 * DOUT];  w0[1] = bp[1 * DOUT];                            \
    w0[2] = bp[2 * DOUT];  w0[3] = bp[3 * DOUT];                            \
    w1[0] = bp[4 * DOUT];  w1[1] = bp[5 * DOUT];                            \
    w1[2] = bp[6 * DOUT];  w1[3] = bp[7 * DOUT];                            \
    w2[0] = bp[8 * DOUT];  w2[1] = bp[9 * DOUT];                            \
    w2[2] = bp[10 * DOUT]; w2[3] = bp[11 * DOUT];                           \
    w3[0] = bp[12 * DOUT]; w3[1] = bp[13 * DOUT];                           \
    w3[2] = bp[14 * DOUT]; w3[3] = bp[15 * DOUT];                           \
  }

  a0 = *(const f32x4*)(Aptr + 0);
  a1 = *(const f32x4*)(Aptr + 4);
  FC_LOADB(0);
  split8_h(a0, a1, As + oA, 2048);
  split8_h(w0, w1, Bs + oB0, 4096);
  split8_h(w2, w3, Bs + oB1, 4096);
  __syncthreads();

  for (int st = 0; st < 10; st++) {
    bool more = st < 9;
    if (more) {
      a0 = *(const f32x4*)(Aptr + (st + 1) * 32);
      a1 = *(const f32x4*)(Aptr + (st + 1) * 32 + 4);
      FC_LOADB((st + 1) * 32);
    }
#pragma unroll
    for (int ib = 0; ib < 2; ib++) {
      f16x8 bfr[4];
#pragma unroll
      for (int ni = 0; ni < 4; ni++)
        bfr[ni] = ldfrag(Bs + ib * 4096 + swzB(wn * 64 + ni * 16 + lr, lg));
#pragma unroll
      for (int ia = 0; ia < 2; ia++) {
        if (ia + ib > 1) continue;
        f16x8 afr[2];
#pragma unroll
        for (int mi = 0; mi < 2; mi++)
          afr[mi] = ldfrag(As + ia * 2048 + swzB(wm * 32 + mi * 16 + lr, lg));
#pragma unroll
        for (int ni = 0; ni < 4; ni++)
#pragma unroll
          for (int mi = 0; mi < 2; mi++)
            acc[mi][ni] = __builtin_amdgcn_mfma_f32_16x16x32_f16(
                afr[mi], bfr[ni], acc[mi][ni], 0, 0, 0);
      }
    }
    __syncthreads();
    if (more) {
      split8_h(a0, a1, As + oA, 2048);
      split8_h(w0, w1, Bs + oB0, 4096);
      split8_h(w2, w3, Bs + oB1, 4096);
    }
    __syncthreads();
  }

  float* p = part + (size_t)kc * (BB * DOUT) + n0;
#pragma unroll
  for (int mi = 0; mi < 2; mi++)
#pragma unroll
    for (int ni = 0; ni < 4; ni++)
#pragma unroll
      for (int j = 0; j < 4; j++)
        p[(size_t)(wm * 32 + mi * 16 + lg * 4 + j) * DOUT + wn * 64 + ni * 16 + lr] =
            acc[mi][ni][j];
}

__global__ __launch_bounds__(256) void k_reduce(const float* __restrict__ part,
                                                const float* __restrict__ b2,
                                                float* __restrict__ out) {
  int idx = blockIdx.x * 256 + threadIdx.x;
  int c = idx & (DOUT - 1);
  float s = 0.f;
  for (int kc = 0; kc < FC_NCH; kc++) s += part[(size_t)kc * BB * DOUT + idx];
  float x = s + b2[c];
  out[idx] = 0.5f * x * (1.0f + erff(x * 0.70710678118654752f));
}

// ---------------- launch ----------------

extern "C" void kernel_launch(void* const* d_in, const int* in_sizes, int n_in,
                              void* d_out, int out_size, void* d_ws, size_t ws_size,
                              hipStream_t stream) {
  (void)in_sizes; (void)n_in; (void)out_size; (void)ws_size;
  const float* tokens = (const float*)d_in[0];
  const float* graph = (const float*)d_in[1];
  const float* W2 = (const float*)d_in[2];
  const float* b2 = (const float*)d_in[3];

  float* ws = (float*)d_ws;
  const long NM = 9437184L;
  float* s1 = ws + NM;        // ZT
  float* s2 = ws + 2 * NM;    // WZT (ld 384)
  float* s3 = ws + 3 * NM;    // M2 (raw, unscaled)
  float* s4 = ws + 4 * NM;    // P1
  float* s5 = ws + 5 * NM;    // Y2
  float* s6 = ws + 6 * NM;    // T
  float* s7 = ws + 7 * NM;    // V (packed triu)
  float* s8 = ws + 8 * NM;    // part
  float* colw = ws + 9 * NM;            // (unused; layout anchor)
  float* wmv = colw + BB * NSEQ;        // (unused)
  float* trv = wmv + BB * DI;
  float* colwp = trv + BB;              // 8*64*256 partials
  float* wmp = colwp + 8 * BB * NSEQ;   // 8*64*384 partials
  float* ivd = wmp + 8 * BB * DI;       // 64*256 inv-degrees

  k_colw1<<<dim3(BB, 8), 256, 0, stream>>>(graph, ivd, colwp);
  k_wmean1<<<dim3(BB, 8), 384, 0, stream>>>(colwp, tokens, wmp);
  k_zcT<<<dim3(6, 4, BB), 256, 0, stream>>>(tokens, wmp, s1);

  // WZT[e][n] = sum_k ZT[e][k] * (graph[n][k]*ivd[n])  (NT + BRSCL) -> s2
  gemm_k<0, 0, 0, 0, 1><<<6 * BB, 256, 0, stream>>>(
      s1, graph, s2, nullptr, nullptr, nullptr, ivd, 256, 256, 256,
      98304L, 65536L, 147456L, 1.f, 0.f, 2, 6);
  // M2[d][e] = sum_n ZT[d][n] WZT[e][n]  (NT; M=N=384,K=256) -> s3
  gemm_k<0, 0, 0, 0, 0><<<9 * BB, 256, 0, stream>>>(
      s1, s2, s3, nullptr, nullptr, nullptr, nullptr, 256, 256, 384,
      98304L, 147456L, 147456L, 1.f, 0.f, 3, 9);

  k_trace<<<BB, 256, 0, stream>>>(s3, trv);

  // P1 = NN(M2*inv, M2*inv) -> s4
  gemm_k<0, 1, 1, 1, 0><<<9 * BB, 256, 0, stream>>>(
      s3, s3, s4, nullptr, nullptr, trv, nullptr, 384, 384, 384,
      147456L, 147456L, 147456L, 1.f, 0.f, 3, 9);
  // H = NN(M2*inv, P1); Y2 epilogue -> s5
  gemm_k<1, 1, 1, 0, 0><<<9 * BB, 256, 0, stream>>>(
      s3, s4, s5, s3, s4, trv, nullptr, 384, 384, 384,
      147456L, 147456L, 147456L, 0.f, 0.f, 3, 9);
  // T = 3I - NN(M2*inv, Y2) -> s6
  gemm_k<0, 1, 1, 0, 0><<<9 * BB, 256, 0, stream>>>(
      s3, s5, s6, nullptr, nullptr, trv, nullptr, 384, 384, 384,
      147456L, 147456L, 147456L, -1.f, 3.f, 3, 9);
  // V = triu(0.5 * NN(Y2, T)) / sqrt(tr+eps) -> s7 (packed; upper tiles only)
  gemm_k<2, 1, 0, 0, 0><<<6 * BB, 256, 0, stream>>>(
      s5, s6, s7, nullptr, nullptr, trv, nullptr, 384, 384, 384,
      147456L, 147456L, 0L, 0.5f, 0.f, 3, 6);

  // part[kc] = V @ W2 chunk; then out = gelu(sum + b2)
  k_fc<<<dim3(4, FC_NCH), 256, 0, stream>>>(s7, W2, s8);
  k_reduce<<<(BB * DOUT) / 256, 256, 0, stream>>>(s8, b2, (float*)d_out);
}